// Round 5
// baseline (268.526 us; speedup 1.0000x reference)
//
#include <hip/hip_runtime.h>

typedef short short8 __attribute__((ext_vector_type(8)));
typedef float floatx4 __attribute__((ext_vector_type(4)));
typedef float floatx16 __attribute__((ext_vector_type(16)));
typedef unsigned short ushort4v __attribute__((ext_vector_type(4)));

#define DEV static __device__ __forceinline__

// fp32 -> bf16 round-to-nearest-even
DEV unsigned short f2bf(float f) {
  unsigned int u = __builtin_bit_cast(unsigned int, f);
  u += 0x7fffu + ((u >> 16) & 1u);
  return (unsigned short)(u >> 16);
}

// pack two fp32 -> bf16x2 via HW cvt (1 VALU op vs ~4 for bit-pack)
DEV unsigned int cvtpk(float a, float b) {
  unsigned int r;
  asm("v_cvt_pk_bf16_f32 %0, %1, %2" : "=v"(r) : "v"(a), "v"(b));
  return r;
}

// async global->LDS, 16B per lane (dest = wave-uniform base + lane*16)
DEV void gload16(const unsigned short* g, unsigned short* l) {
  __builtin_amdgcn_global_load_lds((__attribute__((address_space(1))) void*)g,
                                   (__attribute__((address_space(3))) void*)l,
                                   16, 0, 0);
}

// ---------------------------------------------------------------------------
// Kernel 1: fp32 -> bf16 conversion for X (4M), Wq|Wk|Wv (3M concat), Wo (1M)
// ---------------------------------------------------------------------------
__global__ void convert_kernel(const float* __restrict__ hs, const float* __restrict__ Wq,
                               const float* __restrict__ Wk, const float* __restrict__ Wv,
                               const float* __restrict__ Wo,
                               unsigned short* __restrict__ xbf, unsigned short* __restrict__ wqkv,
                               unsigned short* __restrict__ wobf) {
  size_t i4 = ((size_t)blockIdx.x * 256 + threadIdx.x) * 4;
  const float* src;
  unsigned short* dst;
  if (i4 < 4194304) {
    src = hs + i4; dst = xbf + i4;
  } else if (i4 < 7340032) {
    size_t o = i4 - 4194304;
    size_t lo = o & 1048575;
    src = (o < 1048576) ? (Wq + lo) : ((o < 2097152) ? (Wk + lo) : (Wv + lo));
    dst = wqkv + o;
  } else {
    size_t o = i4 - 7340032;
    src = Wo + o; dst = wobf + o;
  }
  float4 v = *(const float4*)src;
  ushort4v u;
  u.x = f2bf(v.x); u.y = f2bf(v.y); u.z = f2bf(v.z); u.w = f2bf(v.w);
  *(ushort4v*)dst = u;
}

// ---------------------------------------------------------------------------
// Kernel 2: pack attention_mask int32 [B,S,S] -> bitmask [B,S,S/64] u64
// ---------------------------------------------------------------------------
__global__ void maskpack_kernel(const int* __restrict__ mask, unsigned long long* __restrict__ bits) {
  int w = blockIdx.x * 256 + threadIdx.x;  // 131072 words
  const int4* p = (const int4*)(mask + (size_t)w * 64);
  unsigned long long r = 0ull;
#pragma unroll
  for (int j = 0; j < 16; ++j) {
    int4 m = p[j];
    r |= (unsigned long long)(m.x != 0) << (j * 4 + 0);
    r |= (unsigned long long)(m.y != 0) << (j * 4 + 1);
    r |= (unsigned long long)(m.z != 0) << (j * 4 + 2);
    r |= (unsigned long long)(m.w != 0) << (j * 4 + 3);
  }
  bits[w] = r;
}

// ---------------------------------------------------------------------------
// Kernel 3: fused QKV projection. 128x128 tile, BK=32, 4 waves (2x2).
//   nb<16 (Q,K): swapped orientation C^T = W·X^T -> packed 8B stores to [b,h,s,d].
//   nb>=16 (V): normal orientation -> packed 8B stores to V^T [b,h,d,s].
// ---------------------------------------------------------------------------
__global__ void __launch_bounds__(256) qkv_gemm(
    const unsigned short* __restrict__ X, const unsigned short* __restrict__ W,
    const float* __restrict__ bq, const float* __restrict__ bk, const float* __restrict__ bv,
    unsigned short* __restrict__ Qb, unsigned short* __restrict__ Kb,
    unsigned short* __restrict__ Vt) {
  __shared__ __align__(16) unsigned short As[128 * 32];
  __shared__ __align__(16) unsigned short Bs[128 * 32];
  const int tid = threadIdx.x;
  const int lane = tid & 63, wv = tid >> 6;
  const int wm = wv >> 1, wn = wv & 1;
  const int quad = lane >> 4, l15 = lane & 15;
  const int mb = blockIdx.y, nb = blockIdx.x;
  const bool sw = (nb < 16);  // Q/K blocks: swapped operand orientation

  const unsigned short* ga = X + (size_t)(mb * 128 + (tid >> 2)) * 1024 + (tid & 3) * 8;
  const unsigned short* gb = W + (size_t)(nb * 128 + (tid >> 2)) * 1024 + (tid & 3) * 8;
  unsigned short* la1 = As + tid * 8;
  unsigned short* la2 = As + 2048 + tid * 8;
  unsigned short* lb1 = Bs + tid * 8;
  unsigned short* lb2 = Bs + 2048 + tid * 8;

  const int wx = sw ? wn : wm;  // X-tile row block
  const int ww = sw ? wm : wn;  // W-tile row block

  floatx4 acc[4][4] = {};
  for (int kt = 0; kt < 32; ++kt) {
    const int k0 = kt * 32;
    gload16(ga + k0, la1);
    gload16(ga + k0 + 65536, la2);   // +64 rows
    gload16(gb + k0, lb1);
    gload16(gb + k0 + 65536, lb2);
    __syncthreads();
    short8 xa[4], wb[4];
#pragma unroll
    for (int i = 0; i < 4; ++i) {
      xa[i] = *(const short8*)&As[(wx * 64 + i * 16 + l15) * 32 + quad * 8];
      wb[i] = *(const short8*)&Bs[(ww * 64 + i * 16 + l15) * 32 + quad * 8];
    }
    if (sw) {
#pragma unroll
      for (int mt = 0; mt < 4; ++mt)
#pragma unroll
        for (int nt = 0; nt < 4; ++nt)
          acc[mt][nt] = __builtin_amdgcn_mfma_f32_16x16x32_bf16(wb[mt], xa[nt], acc[mt][nt], 0, 0, 0);
    } else {
#pragma unroll
      for (int mt = 0; mt < 4; ++mt)
#pragma unroll
        for (int nt = 0; nt < 4; ++nt)
          acc[mt][nt] = __builtin_amdgcn_mfma_f32_16x16x32_bf16(xa[mt], wb[nt], acc[mt][nt], 0, 0, 0);
    }
    __syncthreads();
  }

  if (sw) {
    // rows (m) = W-cols, cols (n) = s. d varies along r -> packed 8B stores.
#pragma unroll
    for (int mt = 0; mt < 4; ++mt) {
      const int wc0 = nb * 128 + wm * 64 + mt * 16 + quad * 4;  // W-col for r=0
      const int mat = wc0 >> 10;          // 0=Q, 1=K
      const int nl0 = wc0 & 1023;
      const int hh = nl0 >> 6, d0 = nl0 & 63;
      const float4 b4 = *(const float4*)((mat ? bk : bq) + nl0);
      unsigned short* dst = mat ? Kb : Qb;
#pragma unroll
      for (int nt = 0; nt < 4; ++nt) {
        const int colx = mb * 128 + wn * 64 + nt * 16 + l15;    // s index
        const int bb = colx >> 11, s = colx & 2047;
        ushort4v pv;
        pv[0] = f2bf(acc[mt][nt][0] + b4.x);
        pv[1] = f2bf(acc[mt][nt][1] + b4.y);
        pv[2] = f2bf(acc[mt][nt][2] + b4.z);
        pv[3] = f2bf(acc[mt][nt][3] + b4.w);
        *(ushort4v*)&dst[((size_t)(bb * 16 + hh) * 2048 + s) * 64 + d0] = pv;
      }
    }
  } else {
    // V: normal orientation; s varies along r -> packed 8B stores into V^T.
#pragma unroll
    for (int nt = 0; nt < 4; ++nt) {
      const int col = nb * 128 + wn * 64 + nt * 16 + l15;  // in [2048,3072)
      const int nl = col & 1023;
      const float bias = bv[nl];
      const int hh = nl >> 6, d = nl & 63;
#pragma unroll
      for (int mt = 0; mt < 4; ++mt) {
        const int row0 = mb * 128 + wm * 64 + mt * 16 + quad * 4;
        const int bb = row0 >> 11, s = row0 & 2047;
        ushort4v pv;
#pragma unroll
        for (int r = 0; r < 4; ++r) pv[r] = f2bf(acc[mt][nt][r] + bias);
        *(ushort4v*)&Vt[((size_t)(bb * 16 + hh) * 64 + d) * 2048 + s] = pv;
      }
    }
  }
}

// ---------------------------------------------------------------------------
// Kernel 4: flash attention, k-split + double-buffer, 512-thread blocks.
//   512 blocks (XCD-swizzled, 64/XCD) = 32 (b,h) x 16 q-tiles of 128.
//   8 waves = 4 q-groups (qg) x 2 k-halves (h2); each k-half does 1024 k into
//   private acc_o/lsum; merged via LDS epilogue. 16 waves/CU = 4/SIMD.
//   LDS 64KB (2buf x {K0,K1,V0,V1} x 8KB) -> exactly 2 blocks/CU: the
//   allocator's own occupancy math then budgets 128 VGPRs (R1/R2 behavior) —
//   R3/R4's 32KB config made it target 8 waves/EU, cap 64 VGPR, and spill
//   52MB/dispatch (WRITE_SIZE 61MB). Attributes pin it as well.
//   Staging: wave wv stages kind k2=wv>>1 (K0/K1/V0/V1), 4 gload16 calls,
//   pre-swizzled global source (chunk' = c^(row&7)), linear LDS dest.
//   Per-32k block: QK(4 MFMA) -> mask -> exp2+cvtpk -> permlane32_swap ->
//   PV(4 MFMA), only one floatx16 transient live. Fixed-max softmax.
// ---------------------------------------------------------------------------
__global__ __attribute__((amdgpu_flat_work_group_size(512, 512), amdgpu_waves_per_eu(4, 4)))
void attn_kernel(
    const unsigned short* __restrict__ Qb, const unsigned short* __restrict__ Kb,
    const unsigned short* __restrict__ Vt, const unsigned long long* __restrict__ mbits,
    unsigned short* __restrict__ ctx) {
  __shared__ __align__(16) unsigned short SM[2 * 4 * 4096];  // 64KB
  const int tid = threadIdx.x;            // 0..511
  const int lane = tid & 63, wv = tid >> 6;
  const int l31 = lane & 31, h = lane >> 5;
  const int qg = wv & 3, h2 = wv >> 2;    // q-group, k-half
  const int k2 = wv >> 1, sb = (wv & 1) * 4;  // staging kind + slot base
  // XCD swizzle: 64 consecutive work-ids (4 pairs) land on one XCD's L2
  const int bid = (blockIdx.x & 7) * 64 + (blockIdx.x >> 3);
  const int pair = bid >> 4, qt = bid & 15;
  const int b_ = pair >> 4, hd = pair & 15;
  const int qrow = qt * 128 + qg * 32 + l31;        // this lane's q row
  const size_t pbase = (size_t)pair * (2048 * 64);
  const size_t vtb = (size_t)pair * (64 * 2048);

  // Q B-frags: B[k=(lane>>5)*8+j][n=lane&31] -> lane reads Q[qrow][ks*16+h*8 ..+8]
  short8 qf[4];
#pragma unroll
  for (int ks = 0; ks < 4; ++ks)
    qf[ks] = *(const short8*)(Qb + pbase + (size_t)qrow * 64 + ks * 16 + h * 8);

  // staging lane constants: slot c covers rows c*8..c*8+7; chunk'=lane&7,
  // src chunk = (lane&7)^(row&7), row&7 = lane>>3.
  const int kLane = (lane >> 3) * 64 + (((lane & 7) ^ (lane >> 3)) * 8);
  const int vLane = (lane >> 3) * 2048 + (((lane & 7) ^ (lane >> 3)) * 8);
  // per-wave source bases: K kinds advance by 4096/tile, V kinds by 64/tile
  const unsigned short* kbase = Kb + pbase + (size_t)((k2 & 1) * 16) * 4096;
  const unsigned short* vbase = Vt + vtb + (size_t)((k2 & 1) * 16) * 64;
  unsigned short* ldst0 = SM + k2 * 4096 + sb * 512 + lane * 8;  // buf 0 dest

  const unsigned long long* mrow = mbits + ((size_t)b_ * 2048 + qrow) * 32;

  // prologue: stage tile 0 into buffer 0
  if (k2 < 2) {
    const unsigned short* s = kbase + sb * 512 + kLane;
#pragma unroll
    for (int i = 0; i < 4; ++i) gload16(s + i * 512, ldst0 + i * 512);
  } else {
    const unsigned short* s = vbase + sb * 16384 + vLane;
#pragma unroll
    for (int i = 0; i < 4; ++i) gload16(s + i * 16384, ldst0 + i * 512);
  }
  unsigned long long w = mrow[h2 * 16];
  __syncthreads();

  floatx16 acc_o[2] = {};
  float lacc[2] = {0.f, 0.f};
  const float SCL = 0.125f * 1.44269504088896340736f;  // 1/sqrt(64) * log2(e)
  const float NC = -10.0f;

  for (int it = 0; it < 16; ++it) {
    const int cur = it & 1;
    const unsigned short* Kh = SM + cur * 16384 + h2 * 4096;
    const unsigned short* Vh = SM + cur * 16384 + (2 + h2) * 4096;

    // issue next tile's async loads into the other buffer (complete by barrier)
    if (it < 15) {
      unsigned short* dst = ldst0 + (cur ^ 1) * 16384;
      if (k2 < 2) {
        const unsigned short* s = kbase + (size_t)(it + 1) * 4096 + sb * 512 + kLane;
#pragma unroll
        for (int i = 0; i < 4; ++i) gload16(s + i * 512, dst + i * 512);
      } else {
        const unsigned short* s = vbase + (size_t)(it + 1) * 64 + sb * 16384 + vLane;
#pragma unroll
        for (int i = 0; i < 4; ++i) gload16(s + i * 16384, dst + i * 512);
      }
    }
    const unsigned long long nw = (it < 15) ? mrow[h2 * 16 + it + 1] : 0ull;
    const bool needm = __any(w != ~0ull);

    // per 32-k block: QK -> mask -> softmax -> PV (one floatx16 transient)
#pragma unroll
    for (int kb = 0; kb < 2; ++kb) {
      floatx16 accs = {};
      __builtin_amdgcn_s_setprio(1);
#pragma unroll
      for (int ks = 0; ks < 4; ++ks) {
        const int krow = kb * 32 + l31;
        short8 kf = *(const short8*)&Kh[krow * 64 + (((ks * 2 + h) ^ (krow & 7)) * 8)];
        accs = __builtin_amdgcn_mfma_f32_32x32x16_bf16(kf, qf[ks], accs, 0, 0, 0);
      }
      __builtin_amdgcn_s_setprio(0);
      if (needm) {
#pragma unroll
        for (int reg = 0; reg < 16; ++reg) {
          const int kl = (reg & 3) + 8 * (reg >> 2) + 4 * h;
          if (!((w >> (kb * 32 + kl)) & 1ull)) accs[reg] = -6e9f;
        }
      }
      // exp2 + cvt_pk, then permlane32_swap into PV A-frags.
      // pk word contents (h half): pk[4u+0]={4h,4h+1}, pk[4u+1]={4h+2,4h+3},
      // pk[4u+2]={8+4h,..}, pk[4u+3]={8+4h+2,..} (k within 16-block u).
      // swap(pk0,pk2) -> {word0, word2}; swap(pk1,pk3) -> {word1, word3}.
      unsigned int pk[8];
      float ls = 0.f;
#pragma unroll
      for (int i = 0; i < 8; ++i) {
        const float a = exp2f(fmaf(accs[2 * i], SCL, NC));
        const float b = exp2f(fmaf(accs[2 * i + 1], SCL, NC));
        ls += a + b;
        pk[i] = cvtpk(a, b);
      }
      lacc[kb] += ls;
#pragma unroll
      for (int u = 0; u < 2; ++u) {
        auto r02 = __builtin_amdgcn_permlane32_swap(pk[4 * u + 0], pk[4 * u + 2], false, false);
        auto r13 = __builtin_amdgcn_permlane32_swap(pk[4 * u + 1], pk[4 * u + 3], false, false);
        union { unsigned int wd[4]; short8 s8; } af;
        af.wd[0] = r02[0];
        af.wd[1] = r13[0];
        af.wd[2] = r02[1];
        af.wd[3] = r13[1];
        const int t = kb * 2 + u;  // PV k-step (16 s-rows each), t in 0..3
        __builtin_amdgcn_s_setprio(1);
#pragma unroll
        for (int nt = 0; nt < 2; ++nt) {
          const int vrow = nt * 32 + l31;
          short8 vf = *(const short8*)&Vh[vrow * 64 + (((t * 2 + h) ^ (vrow & 7)) * 8)];
          acc_o[nt] = __builtin_amdgcn_mfma_f32_32x32x16_bf16(af.s8, vf, acc_o[nt], 0, 0, 0);
        }
        __builtin_amdgcn_s_setprio(0);
      }
    }
    __syncthreads();   // drains vmcnt: next tile staged; prev buf reusable
    w = nw;
  }

  // fold lsum across the lane-32 halves (complementary k within this k-half)
  float lsum = lacc[0] + lacc[1];
  lsum += __shfl_xor(lsum, 32);

  // k-split merge via LDS: [qg][lane][33] floats (stride 33 -> 2-way banks)
  float* red = (float*)SM;   // 4*64*33*4B = 33.8KB < 64KB, free after barrier
  if (h2 == 1) {
    float* p = red + (qg * 64 + lane) * 33;
#pragma unroll
    for (int reg = 0; reg < 16; ++reg) {
      p[reg] = acc_o[0][reg];
      p[16 + reg] = acc_o[1][reg];
    }
    p[32] = lsum;
  }
  __syncthreads();
  if (h2 == 0) {
    const float* p = red + (qg * 64 + lane) * 33;
#pragma unroll
    for (int reg = 0; reg < 16; ++reg) {
      acc_o[0][reg] += p[reg];
      acc_o[1][reg] += p[16 + reg];
    }
    lsum += p[32];
    const float rinv = 1.f / ((lsum > 0.f) ? lsum : 1.f);
    // epilogue: acc_o C-layout row=q_local, col=d_local; ctx[b, s, hd*64+d]
#pragma unroll
    for (int reg = 0; reg < 16; ++reg) {
      const int ql = (reg & 3) + 8 * (reg >> 2) + 4 * h;
      const float rl = __shfl(rinv, ql);
      const size_t base = ((size_t)b_ * 2048 + qt * 128 + qg * 32 + ql) * 1024 + hd * 64;
      ctx[base + l31]      = f2bf(acc_o[0][reg] * rl);
      ctx[base + 32 + l31] = f2bf(acc_o[1][reg] * rl);
    }
  }
}

// ---------------------------------------------------------------------------
// Kernel 5: output projection. out[m][e] = sum_d ctx[m][d]*Wo[e][d] + bo[e]
//   M=4096, N=1024, fp32 output.
// ---------------------------------------------------------------------------
__global__ void __launch_bounds__(256) out_gemm(
    const unsigned short* __restrict__ C, const unsigned short* __restrict__ W,
    const float* __restrict__ bo, float* __restrict__ out) {
  __shared__ __align__(16) unsigned short As[128 * 32];
  __shared__ __align__(16) unsigned short Bs[128 * 32];
  const int tid = threadIdx.x;
  const int lane = tid & 63, wv = tid >> 6;
  const int wm = wv >> 1, wn = wv & 1;
  const int quad = lane >> 4, l15 = lane & 15;
  const int mb = blockIdx.y, nb = blockIdx.x;

  const unsigned short* ga = C + (size_t)(mb * 128 + (tid >> 2)) * 1024 + (tid & 3) * 8;
  const unsigned short* gb = W + (size_t)(nb * 128 + (tid >> 2)) * 1024 + (tid & 3) * 8;
  unsigned short* la1 = As + tid * 8;
  unsigned short* la2 = As + 2048 + tid * 8;
  unsigned short* lb1 = Bs + tid * 8;
  unsigned short* lb2 = Bs + 2048 + tid * 8;

  floatx4 acc[4][4] = {};
  for (int kt = 0; kt < 32; ++kt) {
    const int k0 = kt * 32;
    gload16(ga + k0, la1);
    gload16(ga + k0 + 65536, la2);
    gload16(gb + k0, lb1);
    gload16(gb + k0 + 65536, lb2);
    __syncthreads();
    short8 af[4], bfr[4];
#pragma unroll
    for (int i = 0; i < 4; ++i) {
      af[i]  = *(const short8*)&As[(wm * 64 + i * 16 + l15) * 32 + quad * 8];
      bfr[i] = *(const short8*)&Bs[(wn * 64 + i * 16 + l15) * 32 + quad * 8];
    }
#pragma unroll
    for (int mt = 0; mt < 4; ++mt)
#pragma unroll
      for (int nt = 0; nt < 4; ++nt)
        acc[mt][nt] = __builtin_amdgcn_mfma_f32_16x16x32_bf16(af[mt], bfr[nt], acc[mt][nt], 0, 0, 0);
    __syncthreads();
  }
#pragma unroll
  for (int nt = 0; nt < 4; ++nt) {
    const int col = nb * 128 + wn * 64 + nt * 16 + l15;
    const float bias = bo[col];
#pragma unroll
    for (int mt = 0; mt < 4; ++mt)
#pragma unroll
      for (int r = 0; r < 4; ++r) {
        const int row = mb * 128 + wm * 64 + mt * 16 + quad * 4 + r;
        out[(size_t)row * 1024 + col] = acc[mt][nt][r] + bias;
      }
  }
}

// ---------------------------------------------------------------------------
extern "C" void kernel_launch(void* const* d_in, const int* in_sizes, int n_in,
                              void* d_out, int out_size, void* d_ws, size_t ws_size,
                              hipStream_t stream) {
  const float* hs = (const float*)d_in[0];
  const int* mask = (const int*)d_in[1];
  const float* Wq = (const float*)d_in[2];
  const float* bq = (const float*)d_in[3];
  const float* Wk = (const float*)d_in[4];
  const float* bk = (const float*)d_in[5];
  const float* Wv = (const float*)d_in[6];
  const float* bv = (const float*)d_in[7];
  const float* Wo = (const float*)d_in[8];
  const float* bo = (const float*)d_in[9];
  float* out = (float*)d_out;

  char* ws = (char*)d_ws;
  unsigned short* xbf  = (unsigned short*)(ws + 0);          // 4M elems
  unsigned short* wqkv = (unsigned short*)(ws + 8388608);    // 3M
  unsigned short* wobf = (unsigned short*)(ws + 14680064);   // 1M
  unsigned short* Qb   = (unsigned short*)(ws + 16777216);   // 4M
  unsigned short* Kb   = (unsigned short*)(ws + 25165824);   // 4M
  unsigned short* Vt   = (unsigned short*)(ws + 33554432);   // 4M
  unsigned short* ctx  = (unsigned short*)(ws + 41943040);   // 4M
  unsigned long long* mbits = (unsigned long long*)(ws + 50331648);  // 131072 words

  convert_kernel<<<8192, 256, 0, stream>>>(hs, Wq, Wk, Wv, Wo, xbf, wqkv, wobf);
  maskpack_kernel<<<512, 256, 0, stream>>>(mask, mbits);
  qkv_gemm<<<dim3(24, 32), 256, 0, stream>>>(xbf, wqkv, bq, bk, bv, Qb, Kb, Vt);
  attn_kernel<<<512, 512, 0, stream>>>(Qb, Kb, Vt, mbits, ctx);
  out_gemm<<<dim3(8, 32), 256, 0, stream>>>(ctx, wobf, bo, out);
}

// Round 6
// 256.803 us; speedup vs baseline: 1.0456x; 1.0456x over previous
//
#include <hip/hip_runtime.h>

typedef short short8 __attribute__((ext_vector_type(8)));
typedef float floatx4 __attribute__((ext_vector_type(4)));
typedef float floatx16 __attribute__((ext_vector_type(16)));
typedef unsigned short ushort4v __attribute__((ext_vector_type(4)));

#define DEV static __device__ __forceinline__

// fp32 -> bf16 round-to-nearest-even
DEV unsigned short f2bf(float f) {
  unsigned int u = __builtin_bit_cast(unsigned int, f);
  u += 0x7fffu + ((u >> 16) & 1u);
  return (unsigned short)(u >> 16);
}

// pack two fp32 -> bf16x2 via HW cvt (1 VALU op vs ~4 for bit-pack)
DEV unsigned int cvtpk(float a, float b) {
  unsigned int r;
  asm("v_cvt_pk_bf16_f32 %0, %1, %2" : "=v"(r) : "v"(a), "v"(b));
  return r;
}

// async global->LDS, 16B per lane (dest = wave-uniform base + lane*16)
DEV void gload16(const unsigned short* g, unsigned short* l) {
  __builtin_amdgcn_global_load_lds((__attribute__((address_space(1))) void*)g,
                                   (__attribute__((address_space(3))) void*)l,
                                   16, 0, 0);
}

// ---------------------------------------------------------------------------
// Kernel 1: fp32 -> bf16 conversion for X (4M), Wq|Wk|Wv (3M concat), Wo (1M)
// ---------------------------------------------------------------------------
__global__ void convert_kernel(const float* __restrict__ hs, const float* __restrict__ Wq,
                               const float* __restrict__ Wk, const float* __restrict__ Wv,
                               const float* __restrict__ Wo,
                               unsigned short* __restrict__ xbf, unsigned short* __restrict__ wqkv,
                               unsigned short* __restrict__ wobf) {
  size_t i4 = ((size_t)blockIdx.x * 256 + threadIdx.x) * 4;
  const float* src;
  unsigned short* dst;
  if (i4 < 4194304) {
    src = hs + i4; dst = xbf + i4;
  } else if (i4 < 7340032) {
    size_t o = i4 - 4194304;
    size_t lo = o & 1048575;
    src = (o < 1048576) ? (Wq + lo) : ((o < 2097152) ? (Wk + lo) : (Wv + lo));
    dst = wqkv + o;
  } else {
    size_t o = i4 - 7340032;
    src = Wo + o; dst = wobf + o;
  }
  float4 v = *(const float4*)src;
  ushort4v u;
  u.x = f2bf(v.x); u.y = f2bf(v.y); u.z = f2bf(v.z); u.w = f2bf(v.w);
  *(ushort4v*)dst = u;
}

// ---------------------------------------------------------------------------
// Kernel 2: pack attention_mask int32 [B,S,S] -> bitmask [B,S,S/64] u64
// ---------------------------------------------------------------------------
__global__ void maskpack_kernel(const int* __restrict__ mask, unsigned long long* __restrict__ bits) {
  int w = blockIdx.x * 256 + threadIdx.x;  // 131072 words
  const int4* p = (const int4*)(mask + (size_t)w * 64);
  unsigned long long r = 0ull;
#pragma unroll
  for (int j = 0; j < 16; ++j) {
    int4 m = p[j];
    r |= (unsigned long long)(m.x != 0) << (j * 4 + 0);
    r |= (unsigned long long)(m.y != 0) << (j * 4 + 1);
    r |= (unsigned long long)(m.z != 0) << (j * 4 + 2);
    r |= (unsigned long long)(m.w != 0) << (j * 4 + 3);
  }
  bits[w] = r;
}

// ---------------------------------------------------------------------------
// Kernel 3: fused QKV projection. 128x128 tile, BK=32, 4 waves (2x2).
//   nb<16 (Q,K): swapped orientation C^T = W·X^T -> packed 8B stores to [b,h,s,d].
//   nb>=16 (V): normal orientation -> packed 8B stores to V^T [b,h,d,s].
// ---------------------------------------------------------------------------
__global__ void __launch_bounds__(256) qkv_gemm(
    const unsigned short* __restrict__ X, const unsigned short* __restrict__ W,
    const float* __restrict__ bq, const float* __restrict__ bk, const float* __restrict__ bv,
    unsigned short* __restrict__ Qb, unsigned short* __restrict__ Kb,
    unsigned short* __restrict__ Vt) {
  __shared__ __align__(16) unsigned short As[128 * 32];
  __shared__ __align__(16) unsigned short Bs[128 * 32];
  const int tid = threadIdx.x;
  const int lane = tid & 63, wv = tid >> 6;
  const int wm = wv >> 1, wn = wv & 1;
  const int quad = lane >> 4, l15 = lane & 15;
  const int mb = blockIdx.y, nb = blockIdx.x;
  const bool sw = (nb < 16);  // Q/K blocks: swapped operand orientation

  const unsigned short* ga = X + (size_t)(mb * 128 + (tid >> 2)) * 1024 + (tid & 3) * 8;
  const unsigned short* gb = W + (size_t)(nb * 128 + (tid >> 2)) * 1024 + (tid & 3) * 8;
  unsigned short* la1 = As + tid * 8;
  unsigned short* la2 = As + 2048 + tid * 8;
  unsigned short* lb1 = Bs + tid * 8;
  unsigned short* lb2 = Bs + 2048 + tid * 8;

  const int wx = sw ? wn : wm;  // X-tile row block
  const int ww = sw ? wm : wn;  // W-tile row block

  floatx4 acc[4][4] = {};
  for (int kt = 0; kt < 32; ++kt) {
    const int k0 = kt * 32;
    gload16(ga + k0, la1);
    gload16(ga + k0 + 65536, la2);   // +64 rows
    gload16(gb + k0, lb1);
    gload16(gb + k0 + 65536, lb2);
    __syncthreads();
    short8 xa[4], wb[4];
#pragma unroll
    for (int i = 0; i < 4; ++i) {
      xa[i] = *(const short8*)&As[(wx * 64 + i * 16 + l15) * 32 + quad * 8];
      wb[i] = *(const short8*)&Bs[(ww * 64 + i * 16 + l15) * 32 + quad * 8];
    }
    if (sw) {
#pragma unroll
      for (int mt = 0; mt < 4; ++mt)
#pragma unroll
        for (int nt = 0; nt < 4; ++nt)
          acc[mt][nt] = __builtin_amdgcn_mfma_f32_16x16x32_bf16(wb[mt], xa[nt], acc[mt][nt], 0, 0, 0);
    } else {
#pragma unroll
      for (int mt = 0; mt < 4; ++mt)
#pragma unroll
        for (int nt = 0; nt < 4; ++nt)
          acc[mt][nt] = __builtin_amdgcn_mfma_f32_16x16x32_bf16(xa[mt], wb[nt], acc[mt][nt], 0, 0, 0);
    }
    __syncthreads();
  }

  if (sw) {
    // rows (m) = W-cols, cols (n) = s. d varies along r -> packed 8B stores.
#pragma unroll
    for (int mt = 0; mt < 4; ++mt) {
      const int wc0 = nb * 128 + wm * 64 + mt * 16 + quad * 4;  // W-col for r=0
      const int mat = wc0 >> 10;          // 0=Q, 1=K
      const int nl0 = wc0 & 1023;
      const int hh = nl0 >> 6, d0 = nl0 & 63;
      const float4 b4 = *(const float4*)((mat ? bk : bq) + nl0);
      unsigned short* dst = mat ? Kb : Qb;
#pragma unroll
      for (int nt = 0; nt < 4; ++nt) {
        const int colx = mb * 128 + wn * 64 + nt * 16 + l15;    // s index
        const int bb = colx >> 11, s = colx & 2047;
        ushort4v pv;
        pv[0] = f2bf(acc[mt][nt][0] + b4.x);
        pv[1] = f2bf(acc[mt][nt][1] + b4.y);
        pv[2] = f2bf(acc[mt][nt][2] + b4.z);
        pv[3] = f2bf(acc[mt][nt][3] + b4.w);
        *(ushort4v*)&dst[((size_t)(bb * 16 + hh) * 2048 + s) * 64 + d0] = pv;
      }
    }
  } else {
    // V: normal orientation; s varies along r -> packed 8B stores into V^T.
#pragma unroll
    for (int nt = 0; nt < 4; ++nt) {
      const int col = nb * 128 + wn * 64 + nt * 16 + l15;  // in [2048,3072)
      const int nl = col & 1023;
      const float bias = bv[nl];
      const int hh = nl >> 6, d = nl & 63;
#pragma unroll
      for (int mt = 0; mt < 4; ++mt) {
        const int row0 = mb * 128 + wm * 64 + mt * 16 + quad * 4;
        const int bb = row0 >> 11, s = row0 & 2047;
        ushort4v pv;
#pragma unroll
        for (int r = 0; r < 4; ++r) pv[r] = f2bf(acc[mt][nt][r] + bias);
        *(ushort4v*)&Vt[((size_t)(bb * 16 + hh) * 64 + d) * 2048 + s] = pv;
      }
    }
  }
}

// ---------------------------------------------------------------------------
// Kernel 4: flash attention, k-split for occupancy (R3 geometry).
//   1024 blocks (XCD-swizzled) = 32 (b,h) x 32 q-tiles of 64.
//   4 waves = 2 q-groups (qg) x 2 k-halves (h2). Each k-half processes 1024 k
//   into private acc_o/lsum; merged via LDS epilogue. 16 waves/CU = 4/SIMD.
//   LDS 32KB -> 4 blocks/CU.
//   __launch_bounds__(256, 2): empirically the ONLY spelling that yields a
//   128-VGPR allocation (R1/R2). Stating min-waves=4 (R3/R4/R5, bounds or
//   amdgpu_waves_per_eu) makes the allocator target 8 waves/EU -> 64 VGPR
//   -> 45-61MB/dispatch of accumulator spill (WRITE_SIZE evidence).
//   Swizzle: chunk' = c^(row&7), staged with pre-swizzled global source,
//   linear LDS dest (rule #21). C->A k-remap via permlane32_swap; P pack via
//   v_cvt_pk_bf16_f32 (T12). Fixed-max softmax p = exp2(s*scale - 10).
// ---------------------------------------------------------------------------
__global__ void __launch_bounds__(256, 2) attn_kernel(
    const unsigned short* __restrict__ Qb, const unsigned short* __restrict__ Kb,
    const unsigned short* __restrict__ Vt, const unsigned long long* __restrict__ mbits,
    unsigned short* __restrict__ ctx) {
  __shared__ __align__(16) unsigned short SM[4 * 64 * 64];  // 32KB: K0|K1|V0|V1
  const int tid = threadIdx.x;            // 0..255
  const int lane = tid & 63, wv = tid >> 6;
  const int l31 = lane & 31, h = lane >> 5;
  const int qg = wv & 1, h2 = wv >> 1;    // q-group, k-half
  // XCD swizzle: 32 consecutive work-ids (one pair) land on one XCD's L2
  const int bid = (blockIdx.x & 7) * 128 + (blockIdx.x >> 3);
  const int pair = bid >> 5, qt = bid & 31;
  const int b_ = pair >> 4, hd = pair & 15;
  const int qrow = qt * 64 + qg * 32 + l31;         // this lane's q row
  const size_t pbase = (size_t)pair * (2048 * 64);
  const size_t vtb = (size_t)pair * (64 * 2048);

  // Q B-frags: B[k=(lane>>5)*8+j][n=lane&31] -> lane reads Q[qrow][ks*16+h*8 ..+8]
  short8 qf[4];
#pragma unroll
  for (int ks = 0; ks < 4; ++ks)
    qf[ks] = *(const short8*)(Qb + pbase + (size_t)qrow * 64 + ks * 16 + h * 8);

  unsigned short* Kh = SM + h2 * 4096;          // this half's K tile [64][64]
  unsigned short* Vh = SM + 8192 + h2 * 4096;   // this half's V tile [64][64]

  // staging lane constants: call c covers rows c*8..c*8+7; chunk'=lane&7,
  // src chunk = (lane&7)^(row&7), row&7 = lane>>3.
  const int kLane = (lane >> 3) * 64 + (((lane & 7) ^ (lane >> 3)) * 8);
  const int vLane = (lane >> 3) * 2048 + (((lane & 7) ^ (lane >> 3)) * 8);
  const int cb = qg * 4;                        // this wave's 4 call slots

  const unsigned long long* mrow = mbits + ((size_t)b_ * 2048 + qrow) * 32;

  floatx16 acc_o[2] = {};
  float lacc[2] = {0.f, 0.f};
  const float SCL = 0.125f * 1.44269504088896340736f;  // 1/sqrt(64) * log2(e)
  const float NC = -10.0f;

  for (int it = 0; it < 16; ++it) {
    const int tg = h2 * 16 + it;                // global 64-k tile index
    // stage this half's K tile (rows tg*64..) and V^T tile (s-cols tg*64..)
    const unsigned short* kt = Kb + pbase + (size_t)tg * 4096;
    const unsigned short* vt = Vt + vtb + (size_t)tg * 64;
#pragma unroll
    for (int i = 0; i < 4; ++i) {
      gload16(kt + (cb + i) * 512 + kLane, Kh + (cb + i) * 512 + lane * 8);
      gload16(vt + (size_t)(cb + i) * 16384 + vLane, Vh + (cb + i) * 512 + lane * 8);
    }
    const unsigned long long w = mrow[tg];      // mask word, hides under barrier
    __syncthreads();                            // staged data visible

    // St = K·Q^T : accs[kb] C-layout: row=k_local(32), col=q=lane&31
    floatx16 accs[2] = {};
    __builtin_amdgcn_s_setprio(1);
#pragma unroll
    for (int ks = 0; ks < 4; ++ks)
#pragma unroll
      for (int kb = 0; kb < 2; ++kb) {
        const int krow = kb * 32 + l31;
        short8 kf = *(const short8*)&Kh[krow * 64 + (((ks * 2 + h) ^ (krow & 7)) * 8)];
        accs[kb] = __builtin_amdgcn_mfma_f32_32x32x16_bf16(kf, qf[ks], accs[kb], 0, 0, 0);
      }
    __builtin_amdgcn_s_setprio(0);

    // mask (fast path: all bits set)
    if (__any(w != ~0ull)) {
#pragma unroll
      for (int kb = 0; kb < 2; ++kb)
#pragma unroll
        for (int reg = 0; reg < 16; ++reg) {
          const int kl = (reg & 3) + 8 * (reg >> 2) + 4 * h;
          const int bit = kb * 32 + kl;
          if (!((w >> bit) & 1ull)) accs[kb][reg] = -6e9f;
        }
    }

    // per 32-k block: exp2 + cvt_pk, then permlane32_swap into PV A-frags.
    // pk word contents (h half): pk[4u+0]={4h,4h+1}, pk[4u+1]={4h+2,4h+3},
    // pk[4u+2]={8+4h,..}, pk[4u+3]={8+4h+2,..} (k within 16-block u).
    // swap(pk0,pk2) -> {word0, word2}; swap(pk1,pk3) -> {word1, word3}.
#pragma unroll
    for (int kb = 0; kb < 2; ++kb) {
      unsigned int pk[8];
      float ls = 0.f;
#pragma unroll
      for (int i = 0; i < 8; ++i) {
        const float a = exp2f(fmaf(accs[kb][2 * i], SCL, NC));
        const float b = exp2f(fmaf(accs[kb][2 * i + 1], SCL, NC));
        ls += a + b;
        pk[i] = cvtpk(a, b);
      }
      lacc[kb] += ls;
#pragma unroll
      for (int u = 0; u < 2; ++u) {
        auto r02 = __builtin_amdgcn_permlane32_swap(pk[4 * u + 0], pk[4 * u + 2], false, false);
        auto r13 = __builtin_amdgcn_permlane32_swap(pk[4 * u + 1], pk[4 * u + 3], false, false);
        union { unsigned int wd[4]; short8 s8; } af;
        af.wd[0] = r02[0];
        af.wd[1] = r13[0];
        af.wd[2] = r02[1];
        af.wd[3] = r13[1];
        const int t = kb * 2 + u;  // PV k-step (16 s-rows each), t in 0..3
        __builtin_amdgcn_s_setprio(1);
#pragma unroll
        for (int nt = 0; nt < 2; ++nt) {
          const int vrow = nt * 32 + l31;
          short8 vf = *(const short8*)&Vh[vrow * 64 + (((t * 2 + h) ^ (vrow & 7)) * 8)];
          acc_o[nt] = __builtin_amdgcn_mfma_f32_32x32x16_bf16(af.s8, vf, acc_o[nt], 0, 0, 0);
        }
        __builtin_amdgcn_s_setprio(0);
      }
    }
    __syncthreads();                            // compute done; buffers reusable
  }

  // fold lsum across the lane-32 halves (complementary k within this k-half)
  float lsum = lacc[0] + lacc[1];
  lsum += __shfl_xor(lsum, 32);

  // k-split merge via LDS: [qg][lane][33] floats (stride 33 -> 2-way banks)
  float* red = (float*)SM;                      // 16.9KB < 32KB, free after barrier
  if (h2 == 1) {
    float* p = red + (qg * 64 + lane) * 33;
#pragma unroll
    for (int reg = 0; reg < 16; ++reg) {
      p[reg] = acc_o[0][reg];
      p[16 + reg] = acc_o[1][reg];
    }
    p[32] = lsum;
  }
  __syncthreads();
  if (h2 == 0) {
    const float* p = red + (qg * 64 + lane) * 33;
#pragma unroll
    for (int reg = 0; reg < 16; ++reg) {
      acc_o[0][reg] += p[reg];
      acc_o[1][reg] += p[16 + reg];
    }
    lsum += p[32];
    const float rinv = 1.f / ((lsum > 0.f) ? lsum : 1.f);
    // epilogue: acc_o C-layout row=q_local, col=d_local; ctx[b, s, hd*64+d]
#pragma unroll
    for (int reg = 0; reg < 16; ++reg) {
      const int ql = (reg & 3) + 8 * (reg >> 2) + 4 * h;
      const float rl = __shfl(rinv, ql);
      const size_t base = ((size_t)b_ * 2048 + qt * 64 + qg * 32 + ql) * 1024 + hd * 64;
      ctx[base + l31]      = f2bf(acc_o[0][reg] * rl);
      ctx[base + 32 + l31] = f2bf(acc_o[1][reg] * rl);
    }
  }
}

// ---------------------------------------------------------------------------
// Kernel 5: output projection. out[m][e] = sum_d ctx[m][d]*Wo[e][d] + bo[e]
//   M=4096, N=1024, fp32 output.
// ---------------------------------------------------------------------------
__global__ void __launch_bounds__(256) out_gemm(
    const unsigned short* __restrict__ C, const unsigned short* __restrict__ W,
    const float* __restrict__ bo, float* __restrict__ out) {
  __shared__ __align__(16) unsigned short As[128 * 32];
  __shared__ __align__(16) unsigned short Bs[128 * 32];
  const int tid = threadIdx.x;
  const int lane = tid & 63, wv = tid >> 6;
  const int wm = wv >> 1, wn = wv & 1;
  const int quad = lane >> 4, l15 = lane & 15;
  const int mb = blockIdx.y, nb = blockIdx.x;

  const unsigned short* ga = C + (size_t)(mb * 128 + (tid >> 2)) * 1024 + (tid & 3) * 8;
  const unsigned short* gb = W + (size_t)(nb * 128 + (tid >> 2)) * 1024 + (tid & 3) * 8;
  unsigned short* la1 = As + tid * 8;
  unsigned short* la2 = As + 2048 + tid * 8;
  unsigned short* lb1 = Bs + tid * 8;
  unsigned short* lb2 = Bs + 2048 + tid * 8;

  floatx4 acc[4][4] = {};
  for (int kt = 0; kt < 32; ++kt) {
    const int k0 = kt * 32;
    gload16(ga + k0, la1);
    gload16(ga + k0 + 65536, la2);
    gload16(gb + k0, lb1);
    gload16(gb + k0 + 65536, lb2);
    __syncthreads();
    short8 af[4], bfr[4];
#pragma unroll
    for (int i = 0; i < 4; ++i) {
      af[i]  = *(const short8*)&As[(wm * 64 + i * 16 + l15) * 32 + quad * 8];
      bfr[i] = *(const short8*)&Bs[(wn * 64 + i * 16 + l15) * 32 + quad * 8];
    }
#pragma unroll
    for (int mt = 0; mt < 4; ++mt)
#pragma unroll
      for (int nt = 0; nt < 4; ++nt)
        acc[mt][nt] = __builtin_amdgcn_mfma_f32_16x16x32_bf16(af[mt], bfr[nt], acc[mt][nt], 0, 0, 0);
    __syncthreads();
  }
#pragma unroll
  for (int nt = 0; nt < 4; ++nt) {
    const int col = nb * 128 + wn * 64 + nt * 16 + l15;
    const float bias = bo[col];
#pragma unroll
    for (int mt = 0; mt < 4; ++mt)
#pragma unroll
      for (int r = 0; r < 4; ++r) {
        const int row = mb * 128 + wm * 64 + mt * 16 + quad * 4 + r;
        out[(size_t)row * 1024 + col] = acc[mt][nt][r] + bias;
      }
  }
}

// ---------------------------------------------------------------------------
extern "C" void kernel_launch(void* const* d_in, const int* in_sizes, int n_in,
                              void* d_out, int out_size, void* d_ws, size_t ws_size,
                              hipStream_t stream) {
  const float* hs = (const float*)d_in[0];
  const int* mask = (const int*)d_in[1];
  const float* Wq = (const float*)d_in[2];
  const float* bq = (const float*)d_in[3];
  const float* Wk = (const float*)d_in[4];
  const float* bk = (const float*)d_in[5];
  const float* Wv = (const float*)d_in[6];
  const float* bv = (const float*)d_in[7];
  const float* Wo = (const float*)d_in[8];
  const float* bo = (const float*)d_in[9];
  float* out = (float*)d_out;

  char* ws = (char*)d_ws;
  unsigned short* xbf  = (unsigned short*)(ws + 0);          // 4M elems
  unsigned short* wqkv = (unsigned short*)(ws + 8388608);    // 3M
  unsigned short* wobf = (unsigned short*)(ws + 14680064);   // 1M
  unsigned short* Qb   = (unsigned short*)(ws + 16777216);   // 4M
  unsigned short* Kb   = (unsigned short*)(ws + 25165824);   // 4M
  unsigned short* Vt   = (unsigned short*)(ws + 33554432);   // 4M
  unsigned short* ctx  = (unsigned short*)(ws + 41943040);   // 4M
  unsigned long long* mbits = (unsigned long long*)(ws + 50331648);  // 131072 words

  convert_kernel<<<8192, 256, 0, stream>>>(hs, Wq, Wk, Wv, Wo, xbf, wqkv, wobf);
  maskpack_kernel<<<512, 256, 0, stream>>>(mask, mbits);
  qkv_gemm<<<dim3(24, 32), 256, 0, stream>>>(xbf, wqkv, bq, bk, bv, Qb, Kb, Vt);
  attn_kernel<<<1024, 256, 0, stream>>>(Qb, Kb, Vt, mbits, ctx);
  out_gemm<<<dim3(8, 32), 256, 0, stream>>>(ctx, wobf, bo, out);
}

// Round 7
// 254.866 us; speedup vs baseline: 1.0536x; 1.0076x over previous
//
#include <hip/hip_runtime.h>

typedef short short8 __attribute__((ext_vector_type(8)));
typedef float floatx4 __attribute__((ext_vector_type(4)));
typedef float floatx16 __attribute__((ext_vector_type(16)));
typedef unsigned short ushort4v __attribute__((ext_vector_type(4)));

#define DEV static __device__ __forceinline__

// fp32 -> bf16 round-to-nearest-even
DEV unsigned short f2bf(float f) {
  unsigned int u = __builtin_bit_cast(unsigned int, f);
  u += 0x7fffu + ((u >> 16) & 1u);
  return (unsigned short)(u >> 16);
}

// pack two fp32 -> bf16x2 via HW cvt (1 VALU op vs ~4 for bit-pack)
DEV unsigned int cvtpk(float a, float b) {
  unsigned int r;
  asm("v_cvt_pk_bf16_f32 %0, %1, %2" : "=v"(r) : "v"(a), "v"(b));
  return r;
}

// async global->LDS, 16B per lane (dest = wave-uniform base + lane*16)
DEV void gload16(const unsigned short* g, unsigned short* l) {
  __builtin_amdgcn_global_load_lds((__attribute__((address_space(1))) void*)g,
                                   (__attribute__((address_space(3))) void*)l,
                                   16, 0, 0);
}

// ---------------------------------------------------------------------------
// Kernel 1: fp32 -> bf16 conversion for X (4M), Wq|Wk|Wv (3M concat), Wo (1M)
// ---------------------------------------------------------------------------
__global__ void convert_kernel(const float* __restrict__ hs, const float* __restrict__ Wq,
                               const float* __restrict__ Wk, const float* __restrict__ Wv,
                               const float* __restrict__ Wo,
                               unsigned short* __restrict__ xbf, unsigned short* __restrict__ wqkv,
                               unsigned short* __restrict__ wobf) {
  size_t i4 = ((size_t)blockIdx.x * 256 + threadIdx.x) * 4;
  const float* src;
  unsigned short* dst;
  if (i4 < 4194304) {
    src = hs + i4; dst = xbf + i4;
  } else if (i4 < 7340032) {
    size_t o = i4 - 4194304;
    size_t lo = o & 1048575;
    src = (o < 1048576) ? (Wq + lo) : ((o < 2097152) ? (Wk + lo) : (Wv + lo));
    dst = wqkv + o;
  } else {
    size_t o = i4 - 7340032;
    src = Wo + o; dst = wobf + o;
  }
  float4 v = *(const float4*)src;
  ushort4v u;
  u.x = f2bf(v.x); u.y = f2bf(v.y); u.z = f2bf(v.z); u.w = f2bf(v.w);
  *(ushort4v*)dst = u;
}

// ---------------------------------------------------------------------------
// Kernel 2: pack attention_mask int32 [B,S,S] -> bitmask [B,S,S/64] u64
// ---------------------------------------------------------------------------
__global__ void maskpack_kernel(const int* __restrict__ mask, unsigned long long* __restrict__ bits) {
  int w = blockIdx.x * 256 + threadIdx.x;  // 131072 words
  const int4* p = (const int4*)(mask + (size_t)w * 64);
  unsigned long long r = 0ull;
#pragma unroll
  for (int j = 0; j < 16; ++j) {
    int4 m = p[j];
    r |= (unsigned long long)(m.x != 0) << (j * 4 + 0);
    r |= (unsigned long long)(m.y != 0) << (j * 4 + 1);
    r |= (unsigned long long)(m.z != 0) << (j * 4 + 2);
    r |= (unsigned long long)(m.w != 0) << (j * 4 + 3);
  }
  bits[w] = r;
}

// ---------------------------------------------------------------------------
// Kernel 3: fused QKV projection. 128x128 tile, BK=32, 4 waves (2x2).
//   nb<16 (Q,K): swapped orientation C^T = W·X^T -> packed 8B stores to [b,h,s,d].
//   nb>=16 (V): normal orientation -> packed 8B stores to V^T [b,h,d,s].
// ---------------------------------------------------------------------------
__global__ void __launch_bounds__(256) qkv_gemm(
    const unsigned short* __restrict__ X, const unsigned short* __restrict__ W,
    const float* __restrict__ bq, const float* __restrict__ bk, const float* __restrict__ bv,
    unsigned short* __restrict__ Qb, unsigned short* __restrict__ Kb,
    unsigned short* __restrict__ Vt) {
  __shared__ __align__(16) unsigned short As[128 * 32];
  __shared__ __align__(16) unsigned short Bs[128 * 32];
  const int tid = threadIdx.x;
  const int lane = tid & 63, wv = tid >> 6;
  const int wm = wv >> 1, wn = wv & 1;
  const int quad = lane >> 4, l15 = lane & 15;
  const int mb = blockIdx.y, nb = blockIdx.x;
  const bool sw = (nb < 16);  // Q/K blocks: swapped operand orientation

  const unsigned short* ga = X + (size_t)(mb * 128 + (tid >> 2)) * 1024 + (tid & 3) * 8;
  const unsigned short* gb = W + (size_t)(nb * 128 + (tid >> 2)) * 1024 + (tid & 3) * 8;
  unsigned short* la1 = As + tid * 8;
  unsigned short* la2 = As + 2048 + tid * 8;
  unsigned short* lb1 = Bs + tid * 8;
  unsigned short* lb2 = Bs + 2048 + tid * 8;

  const int wx = sw ? wn : wm;  // X-tile row block
  const int ww = sw ? wm : wn;  // W-tile row block

  floatx4 acc[4][4] = {};
  for (int kt = 0; kt < 32; ++kt) {
    const int k0 = kt * 32;
    gload16(ga + k0, la1);
    gload16(ga + k0 + 65536, la2);   // +64 rows
    gload16(gb + k0, lb1);
    gload16(gb + k0 + 65536, lb2);
    __syncthreads();
    short8 xa[4], wb[4];
#pragma unroll
    for (int i = 0; i < 4; ++i) {
      xa[i] = *(const short8*)&As[(wx * 64 + i * 16 + l15) * 32 + quad * 8];
      wb[i] = *(const short8*)&Bs[(ww * 64 + i * 16 + l15) * 32 + quad * 8];
    }
    if (sw) {
#pragma unroll
      for (int mt = 0; mt < 4; ++mt)
#pragma unroll
        for (int nt = 0; nt < 4; ++nt)
          acc[mt][nt] = __builtin_amdgcn_mfma_f32_16x16x32_bf16(wb[mt], xa[nt], acc[mt][nt], 0, 0, 0);
    } else {
#pragma unroll
      for (int mt = 0; mt < 4; ++mt)
#pragma unroll
        for (int nt = 0; nt < 4; ++nt)
          acc[mt][nt] = __builtin_amdgcn_mfma_f32_16x16x32_bf16(xa[mt], wb[nt], acc[mt][nt], 0, 0, 0);
    }
    __syncthreads();
  }

  if (sw) {
    // rows (m) = W-cols, cols (n) = s. d varies along r -> packed 8B stores.
#pragma unroll
    for (int mt = 0; mt < 4; ++mt) {
      const int wc0 = nb * 128 + wm * 64 + mt * 16 + quad * 4;  // W-col for r=0
      const int mat = wc0 >> 10;          // 0=Q, 1=K
      const int nl0 = wc0 & 1023;
      const int hh = nl0 >> 6, d0 = nl0 & 63;
      const float4 b4 = *(const float4*)((mat ? bk : bq) + nl0);
      unsigned short* dst = mat ? Kb : Qb;
#pragma unroll
      for (int nt = 0; nt < 4; ++nt) {
        const int colx = mb * 128 + wn * 64 + nt * 16 + l15;    // s index
        const int bb = colx >> 11, s = colx & 2047;
        ushort4v pv;
        pv[0] = f2bf(acc[mt][nt][0] + b4.x);
        pv[1] = f2bf(acc[mt][nt][1] + b4.y);
        pv[2] = f2bf(acc[mt][nt][2] + b4.z);
        pv[3] = f2bf(acc[mt][nt][3] + b4.w);
        *(ushort4v*)&dst[((size_t)(bb * 16 + hh) * 2048 + s) * 64 + d0] = pv;
      }
    }
  } else {
    // V: normal orientation; s varies along r -> packed 8B stores into V^T.
#pragma unroll
    for (int nt = 0; nt < 4; ++nt) {
      const int col = nb * 128 + wn * 64 + nt * 16 + l15;  // in [2048,3072)
      const int nl = col & 1023;
      const float bias = bv[nl];
      const int hh = nl >> 6, d = nl & 63;
#pragma unroll
      for (int mt = 0; mt < 4; ++mt) {
        const int row0 = mb * 128 + wm * 64 + mt * 16 + quad * 4;
        const int bb = row0 >> 11, s = row0 & 2047;
        ushort4v pv;
#pragma unroll
        for (int r = 0; r < 4; ++r) pv[r] = f2bf(acc[mt][nt][r] + bias);
        *(ushort4v*)&Vt[((size_t)(bb * 16 + hh) * 64 + d) * 2048 + s] = pv;
      }
    }
  }
}

// ---------------------------------------------------------------------------
// Kernel 4: flash attention, k-split + double-buffer in 32KB LDS.
//   1024 blocks (XCD-swizzled) = 32 (b,h) x 32 q-tiles of 64.
//   4 waves = 2 q-groups (qg) x 2 k-halves (h2); each half does 1024 k in
//   32 iterations of 32 k into private acc_o/lsum; merged via LDS epilogue.
//   k-tile 32: K[32][64] (4KB) + V[64][32] (4KB) per half per buffer ->
//   2buf x 2half x 8KB = 32KB total -> 4 blocks/CU retained (R6) AND
//   double-buffered (R2): issue stage(t+1, buf^1) -> compute(t) -> ONE
//   barrier/iter (drains vmcnt under ~500cy compute). R6 was single-buffered:
//   gload -> barrier immediately = full latency exposed every iteration.
//   __launch_bounds__(256, 2): the ONLY spelling yielding a 128-VGPR budget
//   (6-round evidence: min-waves=2 -> 104-128 VGPR clean; min-waves=4 via any
//   attribute -> 64 VGPR + 45-61MB accumulator spill).
//   Staging swizzles (pre-swizzled global src, linear LDS dest, rule #21):
//     K: chunk' = c ^ (row&7)      (8 chunks/row, 128B rows)
//     V: chunk' = c ^ ((row>>1)&3) (4 chunks/row, 64B rows; lane-static)
//   C->A k-remap via permlane32_swap; P pack via v_cvt_pk_bf16_f32 (T12).
//   Fixed-max softmax p = exp2(s*scale - 10).
// ---------------------------------------------------------------------------
__global__ void __launch_bounds__(256, 2) attn_kernel(
    const unsigned short* __restrict__ Qb, const unsigned short* __restrict__ Kb,
    const unsigned short* __restrict__ Vt, const unsigned long long* __restrict__ mbits,
    unsigned short* __restrict__ ctx) {
  __shared__ __align__(16) unsigned short SM[16384];  // 32KB: [buf][half][K|V]
  const int tid = threadIdx.x;            // 0..255
  const int lane = tid & 63, wv = tid >> 6;
  const int l31 = lane & 31, h = lane >> 5;
  const int qg = wv & 1, h2 = wv >> 1;    // q-group, k-half
  // XCD swizzle: 32 consecutive work-ids (one pair) land on one XCD's L2
  const int bid = (blockIdx.x & 7) * 128 + (blockIdx.x >> 3);
  const int pair = bid >> 5, qt = bid & 31;
  const int b_ = pair >> 4, hd = pair & 15;
  const int qrow = qt * 64 + qg * 32 + l31;         // this lane's q row
  const size_t pbase = (size_t)pair * (2048 * 64);
  const size_t vtb = (size_t)pair * (64 * 2048);

  // Q B-frags: B[k=(lane>>5)*8+j][n=lane&31] -> lane reads Q[qrow][ks*16+h*8 ..+8]
  short8 qf[4];
#pragma unroll
  for (int ks = 0; ks < 4; ++ks)
    qf[ks] = *(const short8*)(Qb + pbase + (size_t)qrow * 64 + ks * 16 + h * 8);

  // staging lane constants (pre-swizzled global source, linear LDS dest):
  // K call i covers rows i*8..i*8+7; lane -> row = i*8+(l>>3), chunk' = l&7,
  //   src chunk = (l&7)^(row&7), row&7 = l>>3.
  const int kSrc = (lane >> 3) * 64 + (((lane & 7) ^ (lane >> 3)) * 8);
  // V call i covers rows i*16..+15; lane -> row = i*16+(l>>2), chunk' = l&3,
  //   src chunk = (l&3)^((row>>1)&3), (row>>1)&3 = (l>>3)&3 (lane-static).
  const int vSrc = (lane >> 2) * 2048 + (((lane & 3) ^ ((lane >> 3) & 3)) * 8);

  const unsigned short* kgb = Kb + pbase + (size_t)h2 * (1024 * 64);  // this half's K rows
  const unsigned short* vgb = Vt + vtb + h2 * 1024;                   // this half's s-cols
  unsigned short* ldK = SM + h2 * 4096 + lane * 8;          // buf0 K dest
  unsigned short* ldV = SM + h2 * 4096 + 2048 + lane * 8;   // buf0 V dest

  const unsigned long long* mrow = mbits + ((size_t)b_ * 2048 + qrow) * 32 + h2 * 16;

  floatx16 acc_o[2] = {};
  float lsum = 0.f;
  const float SCL = 0.125f * 1.44269504088896340736f;  // 1/sqrt(64) * log2(e)
  const float NC = -10.0f;

  // prologue: stage tile 0 into buffer 0 (qg=0 -> K, qg=1 -> V)
  if (qg == 0) {
#pragma unroll
    for (int i = 0; i < 4; ++i) gload16(kgb + kSrc + i * 512, ldK + i * 512);
  } else {
#pragma unroll
    for (int i = 0; i < 4; ++i) gload16(vgb + vSrc + (size_t)i * 32768, ldV + i * 512);
  }
  __syncthreads();

  for (int it = 0; it < 32; ++it) {
    const int cur = it & 1;
    const unsigned short* Kh = SM + cur * 8192 + h2 * 4096;
    const unsigned short* Vh = Kh + 2048;

    // issue next tile's async loads into the other buffer (land under compute)
    if (it < 31) {
      const int nb = cur ^ 1;
      if (qg == 0) {
        const unsigned short* s = kgb + (size_t)(it + 1) * 2048 + kSrc;
        unsigned short* d = ldK + nb * 8192;
#pragma unroll
        for (int i = 0; i < 4; ++i) gload16(s + i * 512, d + i * 512);
      } else {
        const unsigned short* s = vgb + (size_t)(it + 1) * 32 + vSrc;
        unsigned short* d = ldV + nb * 8192;
#pragma unroll
        for (int i = 0; i < 4; ++i) gload16(s + (size_t)i * 32768, d + i * 512);
      }
    }
    const unsigned long long w = mrow[it >> 1];  // 64-k word; this tile = half
    const int bitbase = (it & 1) * 32;

    // St = K·Q^T over this 32-k tile: C row=k_local(32), col=q=lane&31
    floatx16 accs = {};
    __builtin_amdgcn_s_setprio(1);
#pragma unroll
    for (int ks = 0; ks < 4; ++ks) {
      short8 kf = *(const short8*)&Kh[l31 * 64 + (((ks * 2 + h) ^ (l31 & 7)) * 8)];
      accs = __builtin_amdgcn_mfma_f32_32x32x16_bf16(kf, qf[ks], accs, 0, 0, 0);
    }
    __builtin_amdgcn_s_setprio(0);

    // mask (fast path: all bits set)
    if (__any(w != ~0ull)) {
#pragma unroll
      for (int reg = 0; reg < 16; ++reg) {
        const int kl = (reg & 3) + 8 * (reg >> 2) + 4 * h;
        if (!((w >> (bitbase + kl)) & 1ull)) accs[reg] = -6e9f;
      }
    }

    // exp2 + cvt_pk, then permlane32_swap into PV A-frags.
    // pk word contents (h half): pk[4u+0]={4h,4h+1}, pk[4u+1]={4h+2,4h+3},
    // pk[4u+2]={8+4h,..}, pk[4u+3]={8+4h+2,..} (k within 16-block u).
    // swap(pk0,pk2) -> {word0, word2}; swap(pk1,pk3) -> {word1, word3}.
    unsigned int pk[8];
    float ls = 0.f;
#pragma unroll
    for (int i = 0; i < 8; ++i) {
      const float a = exp2f(fmaf(accs[2 * i], SCL, NC));
      const float b = exp2f(fmaf(accs[2 * i + 1], SCL, NC));
      ls += a + b;
      pk[i] = cvtpk(a, b);
    }
    lsum += ls;
#pragma unroll
    for (int u = 0; u < 2; ++u) {
      auto r02 = __builtin_amdgcn_permlane32_swap(pk[4 * u + 0], pk[4 * u + 2], false, false);
      auto r13 = __builtin_amdgcn_permlane32_swap(pk[4 * u + 1], pk[4 * u + 3], false, false);
      union { unsigned int wd[4]; short8 s8; } af;
      af.wd[0] = r02[0];
      af.wd[1] = r13[0];
      af.wd[2] = r02[1];
      af.wd[3] = r13[1];
      // PV k-step u covers s-rows u*16..+16 of the tile; V chunk = u*2+h
      __builtin_amdgcn_s_setprio(1);
#pragma unroll
      for (int nt = 0; nt < 2; ++nt) {
        const int vrow = nt * 32 + l31;
        short8 vf = *(const short8*)&Vh[vrow * 32 + (((u * 2 + h) ^ ((vrow >> 1) & 3)) * 8)];
        acc_o[nt] = __builtin_amdgcn_mfma_f32_32x32x16_bf16(af.s8, vf, acc_o[nt], 0, 0, 0);
      }
      __builtin_amdgcn_s_setprio(0);
    }
    __syncthreads();   // drains vmcnt: next tile staged; cur buf reusable
  }

  // fold lsum across the lane-32 halves (complementary k within this k-half)
  lsum += __shfl_xor(lsum, 32);

  // k-split merge via LDS: [qg][lane][33] floats (stride 33 -> 2-way banks)
  float* red = (float*)SM;                      // 16.9KB < 32KB, free after barrier
  if (h2 == 1) {
    float* p = red + (qg * 64 + lane) * 33;
#pragma unroll
    for (int reg = 0; reg < 16; ++reg) {
      p[reg] = acc_o[0][reg];
      p[16 + reg] = acc_o[1][reg];
    }
    p[32] = lsum;
  }
  __syncthreads();
  if (h2 == 0) {
    const float* p = red + (qg * 64 + lane) * 33;
#pragma unroll
    for (int reg = 0; reg < 16; ++reg) {
      acc_o[0][reg] += p[reg];
      acc_o[1][reg] += p[16 + reg];
    }
    lsum += p[32];
    const float rinv = 1.f / ((lsum > 0.f) ? lsum : 1.f);
    // epilogue: acc_o C-layout row=q_local, col=d_local; ctx[b, s, hd*64+d]
#pragma unroll
    for (int reg = 0; reg < 16; ++reg) {
      const int ql = (reg & 3) + 8 * (reg >> 2) + 4 * h;
      const float rl = __shfl(rinv, ql);
      const size_t base = ((size_t)b_ * 2048 + qt * 64 + qg * 32 + ql) * 1024 + hd * 64;
      ctx[base + l31]      = f2bf(acc_o[0][reg] * rl);
      ctx[base + 32 + l31] = f2bf(acc_o[1][reg] * rl);
    }
  }
}

// ---------------------------------------------------------------------------
// Kernel 5: output projection. out[m][e] = sum_d ctx[m][d]*Wo[e][d] + bo[e]
//   M=4096, N=1024, fp32 output.
// ---------------------------------------------------------------------------
__global__ void __launch_bounds__(256) out_gemm(
    const unsigned short* __restrict__ C, const unsigned short* __restrict__ W,
    const float* __restrict__ bo, float* __restrict__ out) {
  __shared__ __align__(16) unsigned short As[128 * 32];
  __shared__ __align__(16) unsigned short Bs[128 * 32];
  const int tid = threadIdx.x;
  const int lane = tid & 63, wv = tid >> 6;
  const int wm = wv >> 1, wn = wv & 1;
  const int quad = lane >> 4, l15 = lane & 15;
  const int mb = blockIdx.y, nb = blockIdx.x;

  const unsigned short* ga = C + (size_t)(mb * 128 + (tid >> 2)) * 1024 + (tid & 3) * 8;
  const unsigned short* gb = W + (size_t)(nb * 128 + (tid >> 2)) * 1024 + (tid & 3) * 8;
  unsigned short* la1 = As + tid * 8;
  unsigned short* la2 = As + 2048 + tid * 8;
  unsigned short* lb1 = Bs + tid * 8;
  unsigned short* lb2 = Bs + 2048 + tid * 8;

  floatx4 acc[4][4] = {};
  for (int kt = 0; kt < 32; ++kt) {
    const int k0 = kt * 32;
    gload16(ga + k0, la1);
    gload16(ga + k0 + 65536, la2);
    gload16(gb + k0, lb1);
    gload16(gb + k0 + 65536, lb2);
    __syncthreads();
    short8 af[4], bfr[4];
#pragma unroll
    for (int i = 0; i < 4; ++i) {
      af[i]  = *(const short8*)&As[(wm * 64 + i * 16 + l15) * 32 + quad * 8];
      bfr[i] = *(const short8*)&Bs[(wn * 64 + i * 16 + l15) * 32 + quad * 8];
    }
#pragma unroll
    for (int mt = 0; mt < 4; ++mt)
#pragma unroll
      for (int nt = 0; nt < 4; ++nt)
        acc[mt][nt] = __builtin_amdgcn_mfma_f32_16x16x32_bf16(af[mt], bfr[nt], acc[mt][nt], 0, 0, 0);
    __syncthreads();
  }
#pragma unroll
  for (int nt = 0; nt < 4; ++nt) {
    const int col = nb * 128 + wn * 64 + nt * 16 + l15;
    const float bias = bo[col];
#pragma unroll
    for (int mt = 0; mt < 4; ++mt)
#pragma unroll
      for (int r = 0; r < 4; ++r) {
        const int row = mb * 128 + wm * 64 + mt * 16 + quad * 4 + r;
        out[(size_t)row * 1024 + col] = acc[mt][nt][r] + bias;
      }
  }
}

// ---------------------------------------------------------------------------
extern "C" void kernel_launch(void* const* d_in, const int* in_sizes, int n_in,
                              void* d_out, int out_size, void* d_ws, size_t ws_size,
                              hipStream_t stream) {
  const float* hs = (const float*)d_in[0];
  const int* mask = (const int*)d_in[1];
  const float* Wq = (const float*)d_in[2];
  const float* bq = (const float*)d_in[3];
  const float* Wk = (const float*)d_in[4];
  const float* bk = (const float*)d_in[5];
  const float* Wv = (const float*)d_in[6];
  const float* bv = (const float*)d_in[7];
  const float* Wo = (const float*)d_in[8];
  const float* bo = (const float*)d_in[9];
  float* out = (float*)d_out;

  char* ws = (char*)d_ws;
  unsigned short* xbf  = (unsigned short*)(ws + 0);          // 4M elems
  unsigned short* wqkv = (unsigned short*)(ws + 8388608);    // 3M
  unsigned short* wobf = (unsigned short*)(ws + 14680064);   // 1M
  unsigned short* Qb   = (unsigned short*)(ws + 16777216);   // 4M
  unsigned short* Kb   = (unsigned short*)(ws + 25165824);   // 4M
  unsigned short* Vt   = (unsigned short*)(ws + 33554432);   // 4M
  unsigned short* ctx  = (unsigned short*)(ws + 41943040);   // 4M
  unsigned long long* mbits = (unsigned long long*)(ws + 50331648);  // 131072 words

  convert_kernel<<<8192, 256, 0, stream>>>(hs, Wq, Wk, Wv, Wo, xbf, wqkv, wobf);
  maskpack_kernel<<<512, 256, 0, stream>>>(mask, mbits);
  qkv_gemm<<<dim3(24, 32), 256, 0, stream>>>(xbf, wqkv, bq, bk, bv, Qb, Kb, Vt);
  attn_kernel<<<1024, 256, 0, stream>>>(Qb, Kb, Vt, mbits, ctx);
  out_gemm<<<dim3(8, 32), 256, 0, stream>>>(ctx, wobf, bo, out);
}

// Round 8
// 247.846 us; speedup vs baseline: 1.0834x; 1.0283x over previous
//
#include <hip/hip_runtime.h>

typedef short short8 __attribute__((ext_vector_type(8)));
typedef float floatx4 __attribute__((ext_vector_type(4)));
typedef float floatx16 __attribute__((ext_vector_type(16)));
typedef unsigned short ushort4v __attribute__((ext_vector_type(4)));

#define DEV static __device__ __forceinline__

// fp32 -> bf16 round-to-nearest-even
DEV unsigned short f2bf(float f) {
  unsigned int u = __builtin_bit_cast(unsigned int, f);
  u += 0x7fffu + ((u >> 16) & 1u);
  return (unsigned short)(u >> 16);
}

// pack two fp32 -> bf16x2 via HW cvt (1 VALU op vs ~4 for bit-pack)
DEV unsigned int cvtpk(float a, float b) {
  unsigned int r;
  asm("v_cvt_pk_bf16_f32 %0, %1, %2" : "=v"(r) : "v"(a), "v"(b));
  return r;
}

// async global->LDS, 16B per lane (dest = wave-uniform base + lane*16)
DEV void gload16(const unsigned short* g, unsigned short* l) {
  __builtin_amdgcn_global_load_lds((__attribute__((address_space(1))) void*)g,
                                   (__attribute__((address_space(3))) void*)l,
                                   16, 0, 0);
}

// ---------------------------------------------------------------------------
// Kernel 1: fp32 -> bf16 conversion for X (4M), Wq|Wk|Wv (3M concat), Wo (1M)
// ---------------------------------------------------------------------------
__global__ void convert_kernel(const float* __restrict__ hs, const float* __restrict__ Wq,
                               const float* __restrict__ Wk, const float* __restrict__ Wv,
                               const float* __restrict__ Wo,
                               unsigned short* __restrict__ xbf, unsigned short* __restrict__ wqkv,
                               unsigned short* __restrict__ wobf) {
  size_t i4 = ((size_t)blockIdx.x * 256 + threadIdx.x) * 4;
  const float* src;
  unsigned short* dst;
  if (i4 < 4194304) {
    src = hs + i4; dst = xbf + i4;
  } else if (i4 < 7340032) {
    size_t o = i4 - 4194304;
    size_t lo = o & 1048575;
    src = (o < 1048576) ? (Wq + lo) : ((o < 2097152) ? (Wk + lo) : (Wv + lo));
    dst = wqkv + o;
  } else {
    size_t o = i4 - 7340032;
    src = Wo + o; dst = wobf + o;
  }
  float4 v = *(const float4*)src;
  ushort4v u;
  u.x = f2bf(v.x); u.y = f2bf(v.y); u.z = f2bf(v.z); u.w = f2bf(v.w);
  *(ushort4v*)dst = u;
}

// ---------------------------------------------------------------------------
// Kernel 2: pack attention_mask int32 [B,S,S] -> bitmask [B,S,S/64] u64
// ---------------------------------------------------------------------------
__global__ void maskpack_kernel(const int* __restrict__ mask, unsigned long long* __restrict__ bits) {
  int w = blockIdx.x * 256 + threadIdx.x;  // 131072 words
  const int4* p = (const int4*)(mask + (size_t)w * 64);
  unsigned long long r = 0ull;
#pragma unroll
  for (int j = 0; j < 16; ++j) {
    int4 m = p[j];
    r |= (unsigned long long)(m.x != 0) << (j * 4 + 0);
    r |= (unsigned long long)(m.y != 0) << (j * 4 + 1);
    r |= (unsigned long long)(m.z != 0) << (j * 4 + 2);
    r |= (unsigned long long)(m.w != 0) << (j * 4 + 3);
  }
  bits[w] = r;
}

// ---------------------------------------------------------------------------
// Kernel 3: fused QKV projection. 128x128 tile, BK=32, 4 waves (2x2).
//   nb<16 (Q,K): swapped orientation C^T = W·X^T.
//     Q -> [b,h,s,d] packed 8B stores (attn reads rows directly).
//     K -> MFMA-FRAGMENT layout: record r=(s>>5)*4+(d0>>4), lane=
//          ((d0>>3)&1)*32+(s&31), elem d0&7. attn loads frags coalesced,
//          global->reg, no LDS.
//   nb>=16 (V): normal orientation -> MFMA-FRAGMENT layout: record
//     (s>>5)*4+((s>>4)&1)*2+(d>>5), lane ((s>>3)&1)*32+(d&31), elem s&7.
//   All epilogue stores remain packed 8B.
// ---------------------------------------------------------------------------
__global__ void __launch_bounds__(256) qkv_gemm(
    const unsigned short* __restrict__ X, const unsigned short* __restrict__ W,
    const float* __restrict__ bq, const float* __restrict__ bk, const float* __restrict__ bv,
    unsigned short* __restrict__ Qb, unsigned short* __restrict__ Kb,
    unsigned short* __restrict__ Vt) {
  __shared__ __align__(16) unsigned short As[128 * 32];
  __shared__ __align__(16) unsigned short Bs[128 * 32];
  const int tid = threadIdx.x;
  const int lane = tid & 63, wv = tid >> 6;
  const int wm = wv >> 1, wn = wv & 1;
  const int quad = lane >> 4, l15 = lane & 15;
  const int mb = blockIdx.y, nb = blockIdx.x;
  const bool sw = (nb < 16);  // Q/K blocks: swapped operand orientation

  const unsigned short* ga = X + (size_t)(mb * 128 + (tid >> 2)) * 1024 + (tid & 3) * 8;
  const unsigned short* gb = W + (size_t)(nb * 128 + (tid >> 2)) * 1024 + (tid & 3) * 8;
  unsigned short* la1 = As + tid * 8;
  unsigned short* la2 = As + 2048 + tid * 8;
  unsigned short* lb1 = Bs + tid * 8;
  unsigned short* lb2 = Bs + 2048 + tid * 8;

  const int wx = sw ? wn : wm;  // X-tile row block
  const int ww = sw ? wm : wn;  // W-tile row block

  floatx4 acc[4][4] = {};
  for (int kt = 0; kt < 32; ++kt) {
    const int k0 = kt * 32;
    gload16(ga + k0, la1);
    gload16(ga + k0 + 65536, la2);   // +64 rows
    gload16(gb + k0, lb1);
    gload16(gb + k0 + 65536, lb2);
    __syncthreads();
    short8 xa[4], wb[4];
#pragma unroll
    for (int i = 0; i < 4; ++i) {
      xa[i] = *(const short8*)&As[(wx * 64 + i * 16 + l15) * 32 + quad * 8];
      wb[i] = *(const short8*)&Bs[(ww * 64 + i * 16 + l15) * 32 + quad * 8];
    }
    if (sw) {
#pragma unroll
      for (int mt = 0; mt < 4; ++mt)
#pragma unroll
        for (int nt = 0; nt < 4; ++nt)
          acc[mt][nt] = __builtin_amdgcn_mfma_f32_16x16x32_bf16(wb[mt], xa[nt], acc[mt][nt], 0, 0, 0);
    } else {
#pragma unroll
      for (int mt = 0; mt < 4; ++mt)
#pragma unroll
        for (int nt = 0; nt < 4; ++nt)
          acc[mt][nt] = __builtin_amdgcn_mfma_f32_16x16x32_bf16(xa[mt], wb[nt], acc[mt][nt], 0, 0, 0);
    }
    __syncthreads();
  }

  if (sw) {
    // rows (m) = W-cols, cols (n) = s. d varies along r -> packed 8B stores.
#pragma unroll
    for (int mt = 0; mt < 4; ++mt) {
      const int wc0 = nb * 128 + wm * 64 + mt * 16 + quad * 4;  // W-col for r=0
      const int mat = wc0 >> 10;          // 0=Q, 1=K
      const int nl0 = wc0 & 1023;
      const int hh = nl0 >> 6, d0 = nl0 & 63;
      const float4 b4 = *(const float4*)((mat ? bk : bq) + nl0);
#pragma unroll
      for (int nt = 0; nt < 4; ++nt) {
        const int colx = mb * 128 + wn * 64 + nt * 16 + l15;    // s index
        const int bb = colx >> 11, s = colx & 2047;
        ushort4v pv;
        pv[0] = f2bf(acc[mt][nt][0] + b4.x);
        pv[1] = f2bf(acc[mt][nt][1] + b4.y);
        pv[2] = f2bf(acc[mt][nt][2] + b4.z);
        pv[3] = f2bf(acc[mt][nt][3] + b4.w);
        if (mat == 0) {
          // Q: row layout [pair][s][d]
          *(ushort4v*)&Qb[((size_t)(bb * 16 + hh) * 2048 + s) * 64 + d0] = pv;
        } else {
          // K: fragment layout
          const size_t idx = (size_t)(bb * 16 + hh) * 131072 + (s >> 5) * 2048 +
                             (d0 >> 4) * 512 + (((d0 >> 3) & 1) * 32 + (s & 31)) * 8 + (d0 & 7);
          *(ushort4v*)&Kb[idx] = pv;
        }
      }
    }
  } else {
    // V: normal orientation; s varies along r -> fragment layout, 8B stores.
#pragma unroll
    for (int nt = 0; nt < 4; ++nt) {
      const int col = nb * 128 + wn * 64 + nt * 16 + l15;  // in [2048,3072)
      const int nl = col & 1023;
      const float bias = bv[nl];
      const int hh = nl >> 6, d = nl & 63;
#pragma unroll
      for (int mt = 0; mt < 4; ++mt) {
        const int row0 = mb * 128 + wm * 64 + mt * 16 + quad * 4;
        const int bb = row0 >> 11, s0 = row0 & 2047;
        ushort4v pv;
#pragma unroll
        for (int r = 0; r < 4; ++r) pv[r] = f2bf(acc[mt][nt][r] + bias);
        const size_t idx = (size_t)(bb * 16 + hh) * 131072 + (s0 >> 5) * 2048 +
                           ((s0 >> 4) & 1) * 1024 + (d >> 5) * 512 +
                           (((s0 >> 3) & 1) * 32 + (d & 31)) * 8 + (s0 & 7);
        *(ushort4v*)&Vt[idx] = pv;
      }
    }
  }
}

// ---------------------------------------------------------------------------
// Kernel 4: flash attention — LDS-FREE main loop.
//   1024 blocks (XCD-swizzled) = 32 (b,h) x 32 q-tiles of 64.
//   4 waves = 2 q-groups x 2 k-halves; each half streams 1024 k in 32
//   iterations of 32 k. K/V are pre-arranged in MFMA-fragment order by
//   qkv_gemm, so each frag is one coalesced global_load_dwordx4 (1KB/wave)
//   straight to registers: NO LDS staging, NO bank conflicts, NO barriers
//   in the loop. Streams are L2-resident (512KB/pair, XCD swizzle).
//   Depth-1 pipeline at zero register cost: kf reloaded (tile t+1) right
//   after QK consumes it; vf reloaded right after PV. ~500cy to cover L2.
//   __launch_bounds__(256, 2): the ONLY spelling yielding a 128-VGPR budget
//   (6-round evidence: min-waves=2 -> clean; min-waves=4 -> 64 VGPR + spill).
//   C->A k-remap via permlane32_swap; P pack via v_cvt_pk_bf16_f32.
//   Fixed-max softmax p = exp2(s*scale - 10). LDS: 16.9KB merge buffer only.
// ---------------------------------------------------------------------------
__global__ void __launch_bounds__(256, 2) attn_kernel(
    const unsigned short* __restrict__ Qb, const unsigned short* __restrict__ Kb,
    const unsigned short* __restrict__ Vt, const unsigned long long* __restrict__ mbits,
    unsigned short* __restrict__ ctx) {
  __shared__ float red[2 * 64 * 33];      // k-split merge only (16.9KB)
  const int tid = threadIdx.x;            // 0..255
  const int lane = tid & 63, wv = tid >> 6;
  const int l31 = lane & 31, h = lane >> 5;
  const int qg = wv & 1, h2 = wv >> 1;    // q-group, k-half
  // XCD swizzle: 32 consecutive work-ids (one pair) land on one XCD's L2
  const int bid = (blockIdx.x & 7) * 128 + (blockIdx.x >> 3);
  const int pair = bid >> 5, qt = bid & 31;
  const int b_ = pair >> 4, hd = pair & 15;
  const int qrow = qt * 64 + qg * 32 + l31;         // this lane's q row

  // Q B-frags: lane reads Q[qrow][ks*16+h*8 ..+8]
  short8 qf[4];
#pragma unroll
  for (int ks = 0; ks < 4; ++ks)
    qf[ks] = *(const short8*)(Qb + (size_t)pair * 131072 + (size_t)qrow * 64 + ks * 16 + h * 8);

  // fragment stream pointers: tile t record base = t*2048 elems; this half
  // starts at t = h2*32. Within a tile: K frag ks at +ks*512; V frag
  // (u*2+nt) at +(u*2+nt)*512. Lane offset lane*8.
  const unsigned short* kp = Kb + (size_t)pair * 131072 + h2 * 65536 + lane * 8;
  const unsigned short* vp = Vt + (size_t)pair * 131072 + h2 * 65536 + lane * 8;

  const unsigned long long* mrow = mbits + ((size_t)b_ * 2048 + qrow) * 32 + h2 * 16;

  // prologue: load tile 0 fragments
  short8 kf[4], vf[4];
#pragma unroll
  for (int i = 0; i < 4; ++i) kf[i] = *(const short8*)(kp + i * 512);
#pragma unroll
  for (int i = 0; i < 4; ++i) vf[i] = *(const short8*)(vp + i * 512);

  floatx16 acc_o[2] = {};
  float lsum = 0.f;
  const float SCL = 0.125f * 1.44269504088896340736f;  // 1/sqrt(64) * log2(e)
  const float NC = -10.0f;

#pragma unroll 2
  for (int it = 0; it < 32; ++it) {
    const unsigned long long w = mrow[it >> 1];
    const int bitbase = (it & 1) * 32;

    // St = K·Q^T over this 32-k tile: C row=k_local(32), col=q=lane&31
    floatx16 accs = {};
    __builtin_amdgcn_s_setprio(1);
#pragma unroll
    for (int ks = 0; ks < 4; ++ks)
      accs = __builtin_amdgcn_mfma_f32_32x32x16_bf16(kf[ks], qf[ks], accs, 0, 0, 0);
    __builtin_amdgcn_s_setprio(0);

    // kf consumed -> issue next tile's K frags (full iteration to land)
    kp += 2048;
#pragma unroll
    for (int i = 0; i < 4; ++i) kf[i] = *(const short8*)(kp + i * 512);

    // mask (fast path: all bits set)
    if (__any(w != ~0ull)) {
#pragma unroll
      for (int reg = 0; reg < 16; ++reg) {
        const int kl = (reg & 3) + 8 * (reg >> 2) + 4 * h;
        if (!((w >> (bitbase + kl)) & 1ull)) accs[reg] = -6e9f;
      }
    }

    // exp2 + cvt_pk, then permlane32_swap into PV A-frags.
    // pk word contents (h half): pk[4u+0]={4h,4h+1}, pk[4u+1]={4h+2,4h+3},
    // pk[4u+2]={8+4h,..}, pk[4u+3]={8+4h+2,..} (k within 16-block u).
    // swap(pk0,pk2) -> {word0, word2}; swap(pk1,pk3) -> {word1, word3}.
    unsigned int pk[8];
    float ls = 0.f;
#pragma unroll
    for (int i = 0; i < 8; ++i) {
      const float a = exp2f(fmaf(accs[2 * i], SCL, NC));
      const float b = exp2f(fmaf(accs[2 * i + 1], SCL, NC));
      ls += a + b;
      pk[i] = cvtpk(a, b);
    }
    lsum += ls;
#pragma unroll
    for (int u = 0; u < 2; ++u) {
      auto r02 = __builtin_amdgcn_permlane32_swap(pk[4 * u + 0], pk[4 * u + 2], false, false);
      auto r13 = __builtin_amdgcn_permlane32_swap(pk[4 * u + 1], pk[4 * u + 3], false, false);
      union { unsigned int wd[4]; short8 s8; } af;
      af.wd[0] = r02[0];
      af.wd[1] = r13[0];
      af.wd[2] = r02[1];
      af.wd[3] = r13[1];
      __builtin_amdgcn_s_setprio(1);
#pragma unroll
      for (int nt = 0; nt < 2; ++nt)
        acc_o[nt] = __builtin_amdgcn_mfma_f32_32x32x16_bf16(af.s8, vf[u * 2 + nt], acc_o[nt], 0, 0, 0);
      __builtin_amdgcn_s_setprio(0);
    }

    // vf consumed -> issue next tile's V frags
    vp += 2048;
#pragma unroll
    for (int i = 0; i < 4; ++i) vf[i] = *(const short8*)(vp + i * 512);
  }

  // fold lsum across the lane-32 halves (complementary k within this k-half)
  lsum += __shfl_xor(lsum, 32);

  // k-split merge via LDS: [qg][lane][33] floats (stride 33 -> 2-way banks)
  if (h2 == 1) {
    float* p = red + (qg * 64 + lane) * 33;
#pragma unroll
    for (int reg = 0; reg < 16; ++reg) {
      p[reg] = acc_o[0][reg];
      p[16 + reg] = acc_o[1][reg];
    }
    p[32] = lsum;
  }
  __syncthreads();
  if (h2 == 0) {
    const float* p = red + (qg * 64 + lane) * 33;
#pragma unroll
    for (int reg = 0; reg < 16; ++reg) {
      acc_o[0][reg] += p[reg];
      acc_o[1][reg] += p[16 + reg];
    }
    lsum += p[32];
    const float rinv = 1.f / ((lsum > 0.f) ? lsum : 1.f);
    // epilogue: acc_o C-layout row=q_local, col=d_local; ctx[b, s, hd*64+d]
#pragma unroll
    for (int reg = 0; reg < 16; ++reg) {
      const int ql = (reg & 3) + 8 * (reg >> 2) + 4 * h;
      const float rl = __shfl(rinv, ql);
      const size_t base = ((size_t)b_ * 2048 + qt * 64 + qg * 32 + ql) * 1024 + hd * 64;
      ctx[base + l31]      = f2bf(acc_o[0][reg] * rl);
      ctx[base + 32 + l31] = f2bf(acc_o[1][reg] * rl);
    }
  }
}

// ---------------------------------------------------------------------------
// Kernel 5: output projection. out[m][e] = sum_d ctx[m][d]*Wo[e][d] + bo[e]
//   M=4096, N=1024, fp32 output.
// ---------------------------------------------------------------------------
__global__ void __launch_bounds__(256) out_gemm(
    const unsigned short* __restrict__ C, const unsigned short* __restrict__ W,
    const float* __restrict__ bo, float* __restrict__ out) {
  __shared__ __align__(16) unsigned short As[128 * 32];
  __shared__ __align__(16) unsigned short Bs[128 * 32];
  const int tid = threadIdx.x;
  const int lane = tid & 63, wv = tid >> 6;
  const int wm = wv >> 1, wn = wv & 1;
  const int quad = lane >> 4, l15 = lane & 15;
  const int mb = blockIdx.y, nb = blockIdx.x;

  const unsigned short* ga = C + (size_t)(mb * 128 + (tid >> 2)) * 1024 + (tid & 3) * 8;
  const unsigned short* gb = W + (size_t)(nb * 128 + (tid >> 2)) * 1024 + (tid & 3) * 8;
  unsigned short* la1 = As + tid * 8;
  unsigned short* la2 = As + 2048 + tid * 8;
  unsigned short* lb1 = Bs + tid * 8;
  unsigned short* lb2 = Bs + 2048 + tid * 8;

  floatx4 acc[4][4] = {};
  for (int kt = 0; kt < 32; ++kt) {
    const int k0 = kt * 32;
    gload16(ga + k0, la1);
    gload16(ga + k0 + 65536, la2);
    gload16(gb + k0, lb1);
    gload16(gb + k0 + 65536, lb2);
    __syncthreads();
    short8 af[4], bfr[4];
#pragma unroll
    for (int i = 0; i < 4; ++i) {
      af[i]  = *(const short8*)&As[(wm * 64 + i * 16 + l15) * 32 + quad * 8];
      bfr[i] = *(const short8*)&Bs[(wn * 64 + i * 16 + l15) * 32 + quad * 8];
    }
#pragma unroll
    for (int mt = 0; mt < 4; ++mt)
#pragma unroll
      for (int nt = 0; nt < 4; ++nt)
        acc[mt][nt] = __builtin_amdgcn_mfma_f32_16x16x32_bf16(af[mt], bfr[nt], acc[mt][nt], 0, 0, 0);
    __syncthreads();
  }
#pragma unroll
  for (int nt = 0; nt < 4; ++nt) {
    const int col = nb * 128 + wn * 64 + nt * 16 + l15;
    const float bias = bo[col];
#pragma unroll
    for (int mt = 0; mt < 4; ++mt)
#pragma unroll
      for (int r = 0; r < 4; ++r) {
        const int row = mb * 128 + wm * 64 + mt * 16 + quad * 4 + r;
        out[(size_t)row * 1024 + col] = acc[mt][nt][r] + bias;
      }
  }
}

// ---------------------------------------------------------------------------
extern "C" void kernel_launch(void* const* d_in, const int* in_sizes, int n_in,
                              void* d_out, int out_size, void* d_ws, size_t ws_size,
                              hipStream_t stream) {
  const float* hs = (const float*)d_in[0];
  const int* mask = (const int*)d_in[1];
  const float* Wq = (const float*)d_in[2];
  const float* bq = (const float*)d_in[3];
  const float* Wk = (const float*)d_in[4];
  const float* bk = (const float*)d_in[5];
  const float* Wv = (const float*)d_in[6];
  const float* bv = (const float*)d_in[7];
  const float* Wo = (const float*)d_in[8];
  const float* bo = (const float*)d_in[9];
  float* out = (float*)d_out;

  char* ws = (char*)d_ws;
  unsigned short* xbf  = (unsigned short*)(ws + 0);          // 4M elems
  unsigned short* wqkv = (unsigned short*)(ws + 8388608);    // 3M
  unsigned short* wobf = (unsigned short*)(ws + 14680064);   // 1M
  unsigned short* Qb   = (unsigned short*)(ws + 16777216);   // 4M
  unsigned short* Kb   = (unsigned short*)(ws + 25165824);   // 4M (K frags)
  unsigned short* Vt   = (unsigned short*)(ws + 33554432);   // 4M (V frags)
  unsigned short* ctx  = (unsigned short*)(ws + 41943040);   // 4M
  unsigned long long* mbits = (unsigned long long*)(ws + 50331648);  // 131072 words

  convert_kernel<<<8192, 256, 0, stream>>>(hs, Wq, Wk, Wv, Wo, xbf, wqkv, wobf);
  maskpack_kernel<<<512, 256, 0, stream>>>(mask, mbits);
  qkv_gemm<<<dim3(24, 32), 256, 0, stream>>>(xbf, wqkv, bq, bk, bv, Qb, Kb, Vt);
  attn_kernel<<<1024, 256, 0, stream>>>(Qb, Kb, Vt, mbits, ctx);
  out_gemm<<<dim3(8, 32), 256, 0, stream>>>(ctx, wobf, bo, out);
}

// Round 9
// 244.118 us; speedup vs baseline: 1.1000x; 1.0153x over previous
//
#include <hip/hip_runtime.h>

typedef short short8 __attribute__((ext_vector_type(8)));
typedef float floatx4 __attribute__((ext_vector_type(4)));
typedef float floatx16 __attribute__((ext_vector_type(16)));
typedef unsigned short ushort4v __attribute__((ext_vector_type(4)));

#define DEV static __device__ __forceinline__

// fp32 -> bf16 round-to-nearest-even
DEV unsigned short f2bf(float f) {
  unsigned int u = __builtin_bit_cast(unsigned int, f);
  u += 0x7fffu + ((u >> 16) & 1u);
  return (unsigned short)(u >> 16);
}

// pack two fp32 -> bf16x2 via HW cvt (1 VALU op vs ~4 for bit-pack)
DEV unsigned int cvtpk(float a, float b) {
  unsigned int r;
  asm("v_cvt_pk_bf16_f32 %0, %1, %2" : "=v"(r) : "v"(a), "v"(b));
  return r;
}

// async global->LDS, 16B per lane (dest = wave-uniform base + lane*16)
DEV void gload16(const unsigned short* g, unsigned short* l) {
  __builtin_amdgcn_global_load_lds((__attribute__((address_space(1))) void*)g,
                                   (__attribute__((address_space(3))) void*)l,
                                   16, 0, 0);
}

// ---------------------------------------------------------------------------
// Kernel 1: fp32 -> bf16 conversion for X (4M), Wq|Wk|Wv (3M concat), Wo (1M)
// ---------------------------------------------------------------------------
__global__ void convert_kernel(const float* __restrict__ hs, const float* __restrict__ Wq,
                               const float* __restrict__ Wk, const float* __restrict__ Wv,
                               const float* __restrict__ Wo,
                               unsigned short* __restrict__ xbf, unsigned short* __restrict__ wqkv,
                               unsigned short* __restrict__ wobf) {
  size_t i4 = ((size_t)blockIdx.x * 256 + threadIdx.x) * 4;
  const float* src;
  unsigned short* dst;
  if (i4 < 4194304) {
    src = hs + i4; dst = xbf + i4;
  } else if (i4 < 7340032) {
    size_t o = i4 - 4194304;
    size_t lo = o & 1048575;
    src = (o < 1048576) ? (Wq + lo) : ((o < 2097152) ? (Wk + lo) : (Wv + lo));
    dst = wqkv + o;
  } else {
    size_t o = i4 - 7340032;
    src = Wo + o; dst = wobf + o;
  }
  float4 v = *(const float4*)src;
  ushort4v u;
  u.x = f2bf(v.x); u.y = f2bf(v.y); u.z = f2bf(v.z); u.w = f2bf(v.w);
  *(ushort4v*)dst = u;
}

// ---------------------------------------------------------------------------
// Kernel 2: pack attention_mask int32 [B,S,S] -> bitmask [B,S,S/64] u64
// ---------------------------------------------------------------------------
__global__ void maskpack_kernel(const int* __restrict__ mask, unsigned long long* __restrict__ bits) {
  int w = blockIdx.x * 256 + threadIdx.x;  // 131072 words
  const int4* p = (const int4*)(mask + (size_t)w * 64);
  unsigned long long r = 0ull;
#pragma unroll
  for (int j = 0; j < 16; ++j) {
    int4 m = p[j];
    r |= (unsigned long long)(m.x != 0) << (j * 4 + 0);
    r |= (unsigned long long)(m.y != 0) << (j * 4 + 1);
    r |= (unsigned long long)(m.z != 0) << (j * 4 + 2);
    r |= (unsigned long long)(m.w != 0) << (j * 4 + 3);
  }
  bits[w] = r;
}

// ---------------------------------------------------------------------------
// Kernel 3: fused QKV projection. 128x128 tile, BK=32, 4 waves (2x2).
//   nb<16 (Q,K): swapped orientation C^T = W·X^T.
//     Q -> [b,h,s,d] packed 8B stores, PRE-SCALED by F = 0.125*log2(e):
//          attn then computes p = exp2(QK) directly (no per-element fma;
//          the dropped fixed bias -10 is a uniform 2^10 scale on p AND lsum,
//          cancelling exactly in the softmax normalize).
//     K -> MFMA-FRAGMENT layout: record r=(s>>5)*4+(d0>>4), lane=
//          ((d0>>3)&1)*32+(s&31), elem d0&7. attn loads frags coalesced,
//          global->reg, no LDS.
//   nb>=16 (V): normal orientation -> MFMA-FRAGMENT layout: record
//     (s>>5)*4+((s>>4)&1)*2+(d>>5), lane ((s>>3)&1)*32+(d&31), elem s&7.
//   All epilogue stores remain packed 8B.
// ---------------------------------------------------------------------------
__global__ void __launch_bounds__(256) qkv_gemm(
    const unsigned short* __restrict__ X, const unsigned short* __restrict__ W,
    const float* __restrict__ bq, const float* __restrict__ bk, const float* __restrict__ bv,
    unsigned short* __restrict__ Qb, unsigned short* __restrict__ Kb,
    unsigned short* __restrict__ Vt) {
  __shared__ __align__(16) unsigned short As[128 * 32];
  __shared__ __align__(16) unsigned short Bs[128 * 32];
  const int tid = threadIdx.x;
  const int lane = tid & 63, wv = tid >> 6;
  const int wm = wv >> 1, wn = wv & 1;
  const int quad = lane >> 4, l15 = lane & 15;
  const int mb = blockIdx.y, nb = blockIdx.x;
  const bool sw = (nb < 16);  // Q/K blocks: swapped operand orientation

  const unsigned short* ga = X + (size_t)(mb * 128 + (tid >> 2)) * 1024 + (tid & 3) * 8;
  const unsigned short* gb = W + (size_t)(nb * 128 + (tid >> 2)) * 1024 + (tid & 3) * 8;
  unsigned short* la1 = As + tid * 8;
  unsigned short* la2 = As + 2048 + tid * 8;
  unsigned short* lb1 = Bs + tid * 8;
  unsigned short* lb2 = Bs + 2048 + tid * 8;

  const int wx = sw ? wn : wm;  // X-tile row block
  const int ww = sw ? wm : wn;  // W-tile row block

  floatx4 acc[4][4] = {};
  for (int kt = 0; kt < 32; ++kt) {
    const int k0 = kt * 32;
    gload16(ga + k0, la1);
    gload16(ga + k0 + 65536, la2);   // +64 rows
    gload16(gb + k0, lb1);
    gload16(gb + k0 + 65536, lb2);
    __syncthreads();
    short8 xa[4], wb[4];
#pragma unroll
    for (int i = 0; i < 4; ++i) {
      xa[i] = *(const short8*)&As[(wx * 64 + i * 16 + l15) * 32 + quad * 8];
      wb[i] = *(const short8*)&Bs[(ww * 64 + i * 16 + l15) * 32 + quad * 8];
    }
    if (sw) {
#pragma unroll
      for (int mt = 0; mt < 4; ++mt)
#pragma unroll
        for (int nt = 0; nt < 4; ++nt)
          acc[mt][nt] = __builtin_amdgcn_mfma_f32_16x16x32_bf16(wb[mt], xa[nt], acc[mt][nt], 0, 0, 0);
    } else {
#pragma unroll
      for (int mt = 0; mt < 4; ++mt)
#pragma unroll
        for (int nt = 0; nt < 4; ++nt)
          acc[mt][nt] = __builtin_amdgcn_mfma_f32_16x16x32_bf16(xa[mt], wb[nt], acc[mt][nt], 0, 0, 0);
    }
    __syncthreads();
  }

  if (sw) {
    // rows (m) = W-cols, cols (n) = s. d varies along r -> packed 8B stores.
#pragma unroll
    for (int mt = 0; mt < 4; ++mt) {
      const int wc0 = nb * 128 + wm * 64 + mt * 16 + quad * 4;  // W-col for r=0
      const int mat = wc0 >> 10;          // 0=Q, 1=K
      const int nl0 = wc0 & 1023;
      const int hh = nl0 >> 6, d0 = nl0 & 63;
      const float4 b4 = *(const float4*)((mat ? bk : bq) + nl0);
      // Q is pre-scaled by F so attn's softmax needs no per-element fma.
      const float fac = mat ? 1.0f : 0.18033688011112042f;  // 0.125*log2(e)
#pragma unroll
      for (int nt = 0; nt < 4; ++nt) {
        const int colx = mb * 128 + wn * 64 + nt * 16 + l15;    // s index
        const int bb = colx >> 11, s = colx & 2047;
        ushort4v pv;
        pv[0] = f2bf((acc[mt][nt][0] + b4.x) * fac);
        pv[1] = f2bf((acc[mt][nt][1] + b4.y) * fac);
        pv[2] = f2bf((acc[mt][nt][2] + b4.z) * fac);
        pv[3] = f2bf((acc[mt][nt][3] + b4.w) * fac);
        if (mat == 0) {
          // Q: row layout [pair][s][d]
          *(ushort4v*)&Qb[((size_t)(bb * 16 + hh) * 2048 + s) * 64 + d0] = pv;
        } else {
          // K: fragment layout
          const size_t idx = (size_t)(bb * 16 + hh) * 131072 + (s >> 5) * 2048 +
                             (d0 >> 4) * 512 + (((d0 >> 3) & 1) * 32 + (s & 31)) * 8 + (d0 & 7);
          *(ushort4v*)&Kb[idx] = pv;
        }
      }
    }
  } else {
    // V: normal orientation; s varies along r -> fragment layout, 8B stores.
#pragma unroll
    for (int nt = 0; nt < 4; ++nt) {
      const int col = nb * 128 + wn * 64 + nt * 16 + l15;  // in [2048,3072)
      const int nl = col & 1023;
      const float bias = bv[nl];
      const int hh = nl >> 6, d = nl & 63;
#pragma unroll
      for (int mt = 0; mt < 4; ++mt) {
        const int row0 = mb * 128 + wm * 64 + mt * 16 + quad * 4;
        const int bb = row0 >> 11, s0 = row0 & 2047;
        ushort4v pv;
#pragma unroll
        for (int r = 0; r < 4; ++r) pv[r] = f2bf(acc[mt][nt][r] + bias);
        const size_t idx = (size_t)(bb * 16 + hh) * 131072 + (s0 >> 5) * 2048 +
                           ((s0 >> 4) & 1) * 1024 + (d >> 5) * 512 +
                           (((s0 >> 3) & 1) * 32 + (d & 31)) * 8 + (s0 & 7);
        *(ushort4v*)&Vt[idx] = pv;
      }
    }
  }
}

// ---------------------------------------------------------------------------
// Kernel 4: flash attention — LDS-FREE main loop, VALU-trimmed.
//   1024 blocks (XCD-swizzled) = 32 (b,h) x 32 q-tiles of 64.
//   4 waves = 2 q-groups x 2 k-halves; each half streams 1024 k in 32
//   iterations of 32 k. K/V pre-arranged in MFMA-fragment order by qkv_gemm:
//   coalesced global_load_dwordx4 straight to registers, no LDS/barriers.
//   R9 VALU trims (R8 showed VALU-issue + chains is the critical path):
//    - Q pre-scaled by 0.125*log2e at projection -> p = exp2f(s) directly
//      (16 fma/iter gone; dropped -10 bias is a uniform 2^10 scale that
//      cancels in the normalize).
//    - persistent zero vector Zv as C-in of the first QK MFMA (16
//      v_mov zero-init/iter gone; +16 VGPR, still in the <=128 bucket).
//    - lsum split into 2 accumulators (chain depth 17 -> 8).
//   __launch_bounds__(256, 2): the ONLY spelling yielding a 128-VGPR budget
//   (6-round evidence: min-waves=2 -> clean; min-waves=4 -> 64 VGPR + spill).
//   C->A k-remap via permlane32_swap; P pack via v_cvt_pk_bf16_f32.
// ---------------------------------------------------------------------------
__global__ void __launch_bounds__(256, 2) attn_kernel(
    const unsigned short* __restrict__ Qb, const unsigned short* __restrict__ Kb,
    const unsigned short* __restrict__ Vt, const unsigned long long* __restrict__ mbits,
    unsigned short* __restrict__ ctx) {
  __shared__ float red[2 * 64 * 33];      // k-split merge only (16.9KB)
  const int tid = threadIdx.x;            // 0..255
  const int lane = tid & 63, wv = tid >> 6;
  const int l31 = lane & 31, h = lane >> 5;
  const int qg = wv & 1, h2 = wv >> 1;    // q-group, k-half
  // XCD swizzle: 32 consecutive work-ids (one pair) land on one XCD's L2
  const int bid = (blockIdx.x & 7) * 128 + (blockIdx.x >> 3);
  const int pair = bid >> 5, qt = bid & 31;
  const int b_ = pair >> 4, hd = pair & 15;
  const int qrow = qt * 64 + qg * 32 + l31;         // this lane's q row

  // Q B-frags: lane reads Q[qrow][ks*16+h*8 ..+8]
  short8 qf[4];
#pragma unroll
  for (int ks = 0; ks < 4; ++ks)
    qf[ks] = *(const short8*)(Qb + (size_t)pair * 131072 + (size_t)qrow * 64 + ks * 16 + h * 8);

  // fragment stream pointers: tile t record base = t*2048 elems; this half
  // starts at t = h2*32. Within a tile: K frag ks at +ks*512; V frag
  // (u*2+nt) at +(u*2+nt)*512. Lane offset lane*8.
  const unsigned short* kp = Kb + (size_t)pair * 131072 + h2 * 65536 + lane * 8;
  const unsigned short* vp = Vt + (size_t)pair * 131072 + h2 * 65536 + lane * 8;

  const unsigned long long* mrow = mbits + ((size_t)b_ * 2048 + qrow) * 32 + h2 * 16;

  // prologue: load tile 0 fragments
  short8 kf[4], vf[4];
#pragma unroll
  for (int i = 0; i < 4; ++i) kf[i] = *(const short8*)(kp + i * 512);
#pragma unroll
  for (int i = 0; i < 4; ++i) vf[i] = *(const short8*)(vp + i * 512);

  floatx16 acc_o[2] = {};
  const floatx16 Zv = {};                 // persistent zero C-in for QK MFMA
  float lsum = 0.f;

#pragma unroll 2
  for (int it = 0; it < 32; ++it) {
    const unsigned long long w = mrow[it >> 1];
    const int bitbase = (it & 1) * 32;

    // St = K·Q^T over this 32-k tile: C row=k_local(32), col=q=lane&31
    __builtin_amdgcn_s_setprio(1);
    floatx16 accs = __builtin_amdgcn_mfma_f32_32x32x16_bf16(kf[0], qf[0], Zv, 0, 0, 0);
#pragma unroll
    for (int ks = 1; ks < 4; ++ks)
      accs = __builtin_amdgcn_mfma_f32_32x32x16_bf16(kf[ks], qf[ks], accs, 0, 0, 0);
    __builtin_amdgcn_s_setprio(0);

    // kf consumed -> issue next tile's K frags (full iteration to land)
    kp += 2048;
#pragma unroll
    for (int i = 0; i < 4; ++i) kf[i] = *(const short8*)(kp + i * 512);

    // mask (fast path: all bits set)
    if (__any(w != ~0ull)) {
#pragma unroll
      for (int reg = 0; reg < 16; ++reg) {
        const int kl = (reg & 3) + 8 * (reg >> 2) + 4 * h;
        if (!((w >> (bitbase + kl)) & 1ull)) accs[reg] = -6e9f;
      }
    }

    // p = exp2(s) directly (Q pre-scaled); pack via cvt_pk, then
    // permlane32_swap into PV A-frags.
    // pk word contents (h half): pk[4u+0]={4h,4h+1}, pk[4u+1]={4h+2,4h+3},
    // pk[4u+2]={8+4h,..}, pk[4u+3]={8+4h+2,..} (k within 16-block u).
    // swap(pk0,pk2) -> {word0, word2}; swap(pk1,pk3) -> {word1, word3}.
    unsigned int pk[8];
    float ls0 = 0.f, ls1 = 0.f;
#pragma unroll
    for (int i = 0; i < 8; ++i) {
      const float a = exp2f(accs[2 * i]);
      const float b = exp2f(accs[2 * i + 1]);
      ls0 += a;
      ls1 += b;
      pk[i] = cvtpk(a, b);
    }
    lsum += ls0 + ls1;
#pragma unroll
    for (int u = 0; u < 2; ++u) {
      auto r02 = __builtin_amdgcn_permlane32_swap(pk[4 * u + 0], pk[4 * u + 2], false, false);
      auto r13 = __builtin_amdgcn_permlane32_swap(pk[4 * u + 1], pk[4 * u + 3], false, false);
      union { unsigned int wd[4]; short8 s8; } af;
      af.wd[0] = r02[0];
      af.wd[1] = r13[0];
      af.wd[2] = r02[1];
      af.wd[3] = r13[1];
      __builtin_amdgcn_s_setprio(1);
#pragma unroll
      for (int nt = 0; nt < 2; ++nt)
        acc_o[nt] = __builtin_amdgcn_mfma_f32_32x32x16_bf16(af.s8, vf[u * 2 + nt], acc_o[nt], 0, 0, 0);
      __builtin_amdgcn_s_setprio(0);
    }

    // vf consumed -> issue next tile's V frags
    vp += 2048;
#pragma unroll
    for (int i = 0; i < 4; ++i) vf[i] = *(const short8*)(vp + i * 512);
  }

  // fold lsum across the lane-32 halves (complementary k within this k-half)
  lsum += __shfl_xor(lsum, 32);

  // k-split merge via LDS: [qg][lane][33] floats (stride 33 -> 2-way banks)
  if (h2 == 1) {
    float* p = red + (qg * 64 + lane) * 33;
#pragma unroll
    for (int reg = 0; reg < 16; ++reg) {
      p[reg] = acc_o[0][reg];
      p[16 + reg] = acc_o[1][reg];
    }
    p[32] = lsum;
  }
  __syncthreads();
  if (h2 == 0) {
    const float* p = red + (qg * 64 + lane) * 33;
#pragma unroll
    for (int reg = 0; reg < 16; ++reg) {
      acc_o[0][reg] += p[reg];
      acc_o[1][reg] += p[16 + reg];
    }
    lsum += p[32];
    const float rinv = 1.f / ((lsum > 0.f) ? lsum : 1.f);
    // epilogue: acc_o C-layout row=q_local, col=d_local; ctx[b, s, hd*64+d]
#pragma unroll
    for (int reg = 0; reg < 16; ++reg) {
      const int ql = (reg & 3) + 8 * (reg >> 2) + 4 * h;
      const float rl = __shfl(rinv, ql);
      const size_t base = ((size_t)b_ * 2048 + qt * 64 + qg * 32 + ql) * 1024 + hd * 64;
      ctx[base + l31]      = f2bf(acc_o[0][reg] * rl);
      ctx[base + 32 + l31] = f2bf(acc_o[1][reg] * rl);
    }
  }
}

// ---------------------------------------------------------------------------
// Kernel 5: output projection. out[m][e] = sum_d ctx[m][d]*Wo[e][d] + bo[e]
//   M=4096, N=1024, fp32 output.
// ---------------------------------------------------------------------------
__global__ void __launch_bounds__(256) out_gemm(
    const unsigned short* __restrict__ C, const unsigned short* __restrict__ W,
    const float* __restrict__ bo, float* __restrict__ out) {
  __shared__ __align__(16) unsigned short As[128 * 32];
  __shared__ __align__(16) unsigned short Bs[128 * 32];
  const int tid = threadIdx.x;
  const int lane = tid & 63, wv = tid >> 6;
  const int wm = wv >> 1, wn = wv & 1;
  const int quad = lane >> 4, l15 = lane & 15;
  const int mb = blockIdx.y, nb = blockIdx.x;

  const unsigned short* ga = C + (size_t)(mb * 128 + (tid >> 2)) * 1024 + (tid & 3) * 8;
  const unsigned short* gb = W + (size_t)(nb * 128 + (tid >> 2)) * 1024 + (tid & 3) * 8;
  unsigned short* la1 = As + tid * 8;
  unsigned short* la2 = As + 2048 + tid * 8;
  unsigned short* lb1 = Bs + tid * 8;
  unsigned short* lb2 = Bs + 2048 + tid * 8;

  floatx4 acc[4][4] = {};
  for (int kt = 0; kt < 32; ++kt) {
    const int k0 = kt * 32;
    gload16(ga + k0, la1);
    gload16(ga + k0 + 65536, la2);
    gload16(gb + k0, lb1);
    gload16(gb + k0 + 65536, lb2);
    __syncthreads();
    short8 af[4], bfr[4];
#pragma unroll
    for (int i = 0; i < 4; ++i) {
      af[i]  = *(const short8*)&As[(wm * 64 + i * 16 + l15) * 32 + quad * 8];
      bfr[i] = *(const short8*)&Bs[(wn * 64 + i * 16 + l15) * 32 + quad * 8];
    }
#pragma unroll
    for (int mt = 0; mt < 4; ++mt)
#pragma unroll
      for (int nt = 0; nt < 4; ++nt)
        acc[mt][nt] = __builtin_amdgcn_mfma_f32_16x16x32_bf16(af[mt], bfr[nt], acc[mt][nt], 0, 0, 0);
    __syncthreads();
  }
#pragma unroll
  for (int nt = 0; nt < 4; ++nt) {
    const int col = nb * 128 + wn * 64 + nt * 16 + l15;
    const float bias = bo[col];
#pragma unroll
    for (int mt = 0; mt < 4; ++mt)
#pragma unroll
      for (int r = 0; r < 4; ++r) {
        const int row = mb * 128 + wm * 64 + mt * 16 + quad * 4 + r;
        out[(size_t)row * 1024 + col] = acc[mt][nt][r] + bias;
      }
  }
}

// ---------------------------------------------------------------------------
extern "C" void kernel_launch(void* const* d_in, const int* in_sizes, int n_in,
                              void* d_out, int out_size, void* d_ws, size_t ws_size,
                              hipStream_t stream) {
  const float* hs = (const float*)d_in[0];
  const int* mask = (const int*)d_in[1];
  const float* Wq = (const float*)d_in[2];
  const float* bq = (const float*)d_in[3];
  const float* Wk = (const float*)d_in[4];
  const float* bk = (const float*)d_in[5];
  const float* Wv = (const float*)d_in[6];
  const float* bv = (const float*)d_in[7];
  const float* Wo = (const float*)d_in[8];
  const float* bo = (const float*)d_in[9];
  float* out = (float*)d_out;

  char* ws = (char*)d_ws;
  unsigned short* xbf  = (unsigned short*)(ws + 0);          // 4M elems
  unsigned short* wqkv = (unsigned short*)(ws + 8388608);    // 3M
  unsigned short* wobf = (unsigned short*)(ws + 14680064);   // 1M
  unsigned short* Qb   = (unsigned short*)(ws + 16777216);   // 4M (Q rows, pre-scaled)
  unsigned short* Kb   = (unsigned short*)(ws + 25165824);   // 4M (K frags)
  unsigned short* Vt   = (unsigned short*)(ws + 33554432);   // 4M (V frags)
  unsigned short* ctx  = (unsigned short*)(ws + 41943040);   // 4M
  unsigned long long* mbits = (unsigned long long*)(ws + 50331648);  // 131072 words

  convert_kernel<<<8192, 256, 0, stream>>>(hs, Wq, Wk, Wv, Wo, xbf, wqkv, wobf);
  maskpack_kernel<<<512, 256, 0, stream>>>(mask, mbits);
  qkv_gemm<<<dim3(24, 32), 256, 0, stream>>>(xbf, wqkv, bq, bk, bv, Qb, Kb, Vt);
  attn_kernel<<<1024, 256, 0, stream>>>(Qb, Kb, Vt, mbits, ctx);
  out_gemm<<<dim3(8, 32), 256, 0, stream>>>(ctx, wobf, bo, out);
}